// Round 7
// baseline (268.475 us; speedup 1.0000x reference)
//
#include <hip/hip_runtime.h>
#include <hip/hip_bf16.h>

typedef __hip_bfloat16 bf16;
typedef __attribute__((ext_vector_type(8))) short short8v;   // 8 bf16 (4 VGPRs)
typedef __attribute__((ext_vector_type(4))) float float4v;   // MFMA C/D frag

// Problem constants
#define UU 1024
#define BB 8
#define DD 512
#define HH 8
#define HD 64
#define RR 64
#define SS 16
#define MM 15
#define QQ 1104   // R + U + S
#define KVL 1103  // M + R + U
#define PEL 2047
#define NU 1536   // fused QKV output width
#define MU 8952   // union rows (15+64+1024+16)*8

#define AS1 __attribute__((address_space(1)))
#define AS3 __attribute__((address_space(3)))

__device__ __forceinline__ float lo16(unsigned u) { return __uint_as_float(u << 16); }
__device__ __forceinline__ float hi16(unsigned u) { return __uint_as_float(u & 0xffff0000u); }
__device__ __forceinline__ unsigned pk2(float a, float b) {
  unsigned short x = __builtin_bit_cast(unsigned short, __float2bfloat16(a));
  unsigned short y = __builtin_bit_cast(unsigned short, __float2bfloat16(b));
  return (unsigned)x | ((unsigned)y << 16);
}

// ---- dtype detection + (fp32 fallback only) canonicalization ----
struct PackDesc {
  const void* src[16];
  unsigned int srcoff[16];
  unsigned int dstoff[16];
  unsigned int cum[17];   // cumulative 8-element chunks
};

__global__ __launch_bounds__(256) void pack_all(PackDesc d, bf16* base,
                                                const void* __restrict__ probe,
                                                int* __restrict__ flagout,
                                                int nchunks) {
  __shared__ int wsum[4];
  const unsigned short* p = (const unsigned short*)probe;
  int big = 0;
  for (int i = threadIdx.x; i < 4096; i += 256)
    big += (((p[i] >> 7) & 0xFF) >= 137) ? 1 : 0;
  #pragma unroll
  for (int off = 32; off; off >>= 1) big += __shfl_down(big, off);
  if ((threadIdx.x & 63) == 0) wsum[threadIdx.x >> 6] = big;
  __syncthreads();
  const int flag = (wsum[0] + wsum[1] + wsum[2] + wsum[3] < 16) ? 1 : 0;
  if (threadIdx.x == 0 && blockIdx.x == 0) *flagout = flag;
  if (flag) return;  // bf16 inputs: consumers read originals directly

  int g = blockIdx.x * 256 + threadIdx.x;
  if (g >= nchunks) return;
  int s = 0;
  #pragma unroll
  for (int i = 1; i < 17; ++i) s += (g >= d.cum[i]) ? 1 : 0;
  unsigned local = (g - d.cum[s]) * 8u;
  bf16* dst = base + d.dstoff[s] + local;
  const float* fp = (const float*)d.src[s] + d.srcoff[s] + local;
  uint4 o;
  o.x = pk2(fp[0], fp[1]);
  o.y = pk2(fp[2], fp[3]);
  o.z = pk2(fp[4], fp[5]);
  o.w = pk2(fp[6], fp[7]);
  *(uint4*)dst = o;
}

// ---- MFMA GEMM, 64x128 tile, BK=128, XOR-swizzled LDS, segmented inputs ----
// X rows resolved through a 4-segment table (zero-copy concat); W through a
// 2-segment table; all segment pointers are (orig, packed) pairs selected by
// *flag at runtime. out[m,n] = X[m,:]·W[n,:] (+bias[n]).
struct GemmP {
  const bf16* xo[4]; const bf16* xp[4]; int xlim[4]; int xbase[4];
  const bf16* wo[2]; const bf16* wp[2]; int wlim0; int wbase1;
  const bf16* bo[2]; const bf16* bp[2]; int hasbias;
  void* out; int M, N, K; int oflag;   // oflag: 0 always bf16, 1 dtype per flag
};

__global__ __launch_bounds__(256) void gemm_dual(GemmP g0, GemmP g1, int ysplit,
                                                 const int* __restrict__ flag) {
  __shared__ bf16 As[64 * 128];
  __shared__ bf16 Bs[128 * 128];
  const bool bf = (*flag != 0);
  GemmP g; int bm, bn;
  if ((int)blockIdx.y < ysplit) {
    g = g0; bm = blockIdx.y * 64; bn = blockIdx.x * 128;
  } else {
    g = g1;
    int nt = g1.N >> 7;
    int bi = ((int)blockIdx.y - ysplit) * gridDim.x + blockIdx.x;
    if (bi >= ((g1.M + 63) >> 6) * nt) return;
    bm = (bi / nt) * 64; bn = (bi % nt) * 128;
  }
  const bf16* xs[4];
  #pragma unroll
  for (int i = 0; i < 4; ++i) xs[i] = bf ? g.xo[i] : g.xp[i];
  const bf16* w0 = bf ? g.wo[0] : g.wp[0];
  const bf16* w1 = bf ? g.wo[1] : g.wp[1];

  const int tid = threadIdx.x;
  const int lane = tid & 63, wv = tid >> 6;
  const int wr = wv >> 1, wc = wv & 1;
  const int lr4 = lane >> 4;           // row within 4-row staging group
  const int lb = lane & 15;            // 16B block within 256B row
  const int quad = lane >> 4, l15 = lane & 15;

  float4v acc[2][4] = {};

  for (int kb = 0; kb < g.K; kb += 128) {
    // stage A: 64 rows x 128 cols (16 KB)
    #pragma unroll
    for (int i = 0; i < 4; ++i) {
      int r = wv * 16 + i * 4 + lr4;
      int gm = bm + r; if (gm > g.M - 1) gm = g.M - 1;
      int s = (gm >= g.xlim[0]) + (gm >= g.xlim[1]) + (gm >= g.xlim[2]);
      const bf16* src = xs[s] + (size_t)(gm - g.xbase[s]) * g.K + kb + ((lb ^ (r & 15)) * 8);
      __builtin_amdgcn_global_load_lds((const AS1 void*)src,
                                       (AS3 void*)&As[(wv * 16 + i * 4) * 128], 16, 0, 0);
    }
    // stage B: 128 rows x 128 cols (32 KB)
    #pragma unroll
    for (int i = 0; i < 8; ++i) {
      int r = wv * 32 + i * 4 + lr4;
      int gn = bn + r; if (gn > g.N - 1) gn = g.N - 1;
      const bf16* src = ((gn < g.wlim0) ? w0 + (size_t)gn * g.K
                                        : w1 + (size_t)(gn - g.wbase1) * g.K)
                        + kb + ((lb ^ (r & 15)) * 8);
      __builtin_amdgcn_global_load_lds((const AS1 void*)src,
                                       (AS3 void*)&Bs[(wv * 32 + i * 4) * 128], 16, 0, 0);
    }
    __syncthreads();
    #pragma unroll
    for (int ki = 0; ki < 4; ++ki) {
      const int slot = ((ki * 4 + quad) ^ l15) * 8;
      short8v a[2], bq[4];
      #pragma unroll
      for (int t = 0; t < 2; ++t)
        a[t] = *(const short8v*)&As[(wr * 32 + t * 16 + l15) * 128 + slot];
      #pragma unroll
      for (int t = 0; t < 4; ++t)
        bq[t] = *(const short8v*)&Bs[(wc * 64 + t * 16 + l15) * 128 + slot];
      #pragma unroll
      for (int mt = 0; mt < 2; ++mt)
        #pragma unroll
        for (int nt = 0; nt < 4; ++nt)
          acc[mt][nt] = __builtin_amdgcn_mfma_f32_16x16x32_bf16(
              a[mt], bq[nt], acc[mt][nt], 0, 0, 0);
    }
    __syncthreads();
  }

  const bool as_bf16 = g.oflag ? bf : true;
  const bf16* b0 = bf ? g.bo[0] : g.bp[0];
  const bf16* b1 = bf ? g.bo[1] : g.bp[1];
  #pragma unroll
  for (int mt = 0; mt < 2; ++mt) {
    #pragma unroll
    for (int r = 0; r < 4; ++r) {
      int gm = bm + wr * 32 + mt * 16 + quad * 4 + r;
      if (gm >= g.M) continue;
      #pragma unroll
      for (int nt = 0; nt < 4; ++nt) {
        int gn = bn + wc * 64 + nt * 16 + l15;
        float v = acc[mt][nt][r];
        if (g.hasbias)
          v += __bfloat162float((gn < g.wlim0) ? b0[gn] : b1[gn - g.wbase1]);
        size_t o = (size_t)gm * g.N + gn;
        if (as_bf16) ((bf16*)g.out)[o] = __float2bfloat16(v);
        else         ((float*)g.out)[o] = v;
      }
    }
  }
}

// ---- MFMA chunk attention: one block per (c, b, h) ----
__device__ __forceinline__ int gcol(int row, int c, int u0, int ncols) {
  if (row < c) return row;
  if (row < c + 4) return 15 + 4 * c + (row - c);
  if (row < ncols) return 79 + u0 + (row - c - 4);
  return 0;
}

__global__ __launch_bounds__(256, 2) void attn_chunk(
    const bf16* __restrict__ qkv, const bf16* __restrict__ pos,
    const bf16* __restrict__ pbu_o, const bf16* __restrict__ pbu_p,
    const bf16* __restrict__ pbv_o, const bf16* __restrict__ pbv_p,
    const int* __restrict__ lengths, bf16* __restrict__ attn,
    const int* __restrict__ flag, void* __restrict__ dout) {
  __shared__ char lds[65536];
  bf16* Vs   = (bf16*)(lds);           // [152][64]  (k>>3)-swizzled, whole life
  bf16* Aqu  = (bf16*)(lds + 19456);   // [80][64]   row&7-swizzled, whole life
  bf16* Kt   = (bf16*)(lds + 29696);   // [152][64]  row&7-swizzled, phase B
  bf16* Aqv  = (bf16*)(lds + 32768);   // [64][64]   row&7-swizzled, phase A
  bf16* Psl  = (bf16*)(lds + 40960);   // [192][64]  row&7-swizzled, phase A
  bf16* Eb   = (bf16*)(lds + 49152);   // [64][128]  bank-swizzled, phase B
  bf16* Pp   = (bf16*)(lds + 19456);   // [80][168]  softmax phase (over Aqu/Kt)
  float* wred  = (float*)(lds + 46336); // [80][4]
  float* rstat = (float*)(lds + 47616); // [80]

  const int idx = blockIdx.x;
  const int h = idx & 7, b = (idx >> 3) & 7, c = idx >> 6;
  const int u0 = c ? (c - 1) * 64 : 0;
  const int nut = c ? 128 : 64;
  const int ncols = c + 4 + nut;
  const int q0 = c ? 63 : 127;     // pos row p = q0 - m + jl
  const int tid = threadIdx.x, lane = tid & 63, wv = tid >> 6;
  const int quad = lane >> 4, l15 = lane & 15, key = l15 & 7;
  const int lenlim = lengths[b] - u0;
  const bool obf = (*flag != 0);
  const bf16* pbu = obf ? pbu_o : pbu_p;
  const bf16* pbv = obf ? pbv_o : pbv_p;

  // ---- stage V (152 rows, (k>>3)&7-swizzle) and PosSel (192 rows) ----
  {
    int lr = lane >> 3;
    int sbr = (lane & 7) ^ lr;
    for (int i = wv; i < 19; i += 4) {
      int row = i * 8 + lr;
      int g = gcol(row, c, u0, ncols);
      int sbv = (lane & 7) ^ (i & 7);
      const bf16* src = qkv + ((size_t)(g * 8 + b)) * NU + 1024 + h * 64 + sbv * 8;
      __builtin_amdgcn_global_load_lds((const AS1 void*)src, (AS3 void*)(Vs + i * 512), 16, 0, 0);
    }
    for (int i = wv; i < 24; i += 4) {
      int p = i * 8 + lr;
      const bf16* src = pos + (size_t)p * 512 + h * 64 + sbr * 8;
      __builtin_amdgcn_global_load_lds((const AS1 void*)src, (AS3 void*)(Psl + i * 512), 16, 0, 0);
    }
  }
  // ---- stage Aqu = q + pbu (80 rows), Aqv = q_utt + pbv (64 rows) ----
  for (int id = tid; id < 1152; id += 256) {
    bool isv = id >= 640;
    int lid = isv ? id - 640 : id;
    int m = lid >> 3, ec = lid & 7;
    int qrow;
    if (isv) qrow = 64 + 64 * c + m;
    else qrow = (m < 64) ? (64 + 64 * c + m)
              : (m < 68) ? (4 * c + (m - 64))
              : (m == 68) ? (1088 + c) : 0;
    const uint4 qa = *(const uint4*)(qkv + ((size_t)((qrow + 15) * 8 + b)) * NU + h * 64 + ec * 8);
    const uint4 ba = *(const uint4*)((isv ? pbv : pbu) + h * 64 + ec * 8);
    uint4 o;
    o.x = pk2(lo16(qa.x) + lo16(ba.x), hi16(qa.x) + hi16(ba.x));
    o.y = pk2(lo16(qa.y) + lo16(ba.y), hi16(qa.y) + hi16(ba.y));
    o.z = pk2(lo16(qa.z) + lo16(ba.z), hi16(qa.z) + hi16(ba.z));
    o.w = pk2(lo16(qa.w) + lo16(ba.w), hi16(qa.w) + hi16(ba.w));
    *(uint4*)((isv ? Aqv : Aqu) + m * 64 + (ec ^ (m & 7)) * 8) = o;
  }
  __syncthreads();  // s1

  // ---- E GEMM: E[64 x 192] = Aqv @ PosSel^T ----
  float4v eacc[4][3];
  #pragma unroll
  for (int mt = 0; mt < 4; ++mt)
    #pragma unroll
    for (int i = 0; i < 3; ++i) eacc[mt][i] = (float4v){0.f, 0.f, 0.f, 0.f};
  {
    short8v av[4][2];
    #pragma unroll
    for (int mt = 0; mt < 4; ++mt)
      #pragma unroll
      for (int ks = 0; ks < 2; ++ks)
        av[mt][ks] = *(const short8v*)&Aqv[(mt * 16 + l15) * 64 + ((ks * 4 + quad) ^ key) * 8];
    #pragma unroll
    for (int nti = 0; nti < 3; ++nti) {
      int nt = wv + nti * 4;
      short8v b0 = *(const short8v*)&Psl[(nt * 16 + l15) * 64 + (quad ^ key) * 8];
      short8v b1 = *(const short8v*)&Psl[(nt * 16 + l15) * 64 + ((4 + quad) ^ key) * 8];
      #pragma unroll
      for (int mt = 0; mt < 4; ++mt) {
        eacc[mt][nti] = __builtin_amdgcn_mfma_f32_16x16x32_bf16(av[mt][0], b0, eacc[mt][nti], 0, 0, 0);
        eacc[mt][nti] = __builtin_amdgcn_mfma_f32_16x16x32_bf16(av[mt][1], b1, eacc[mt][nti], 0, 0, 0);
      }
    }
  }
  __syncthreads();  // s2: Aqv/Psl dead

  // ---- stage K (row&7-swizzle) + scatter E into Eb (bank-swizzled) ----
  {
    int lr = lane >> 3, sbr = (lane & 7) ^ lr;
    for (int i = wv; i < 19; i += 4) {
      int row = i * 8 + lr;
      int g = gcol(row, c, u0, ncols);
      const bf16* src = qkv + ((size_t)(g * 8 + b)) * NU + 512 + h * 64 + sbr * 8;
      __builtin_amdgcn_global_load_lds((const AS1 void*)src, (AS3 void*)(Kt + i * 512), 16, 0, 0);
    }
  }
  #pragma unroll
  for (int nti = 0; nti < 3; ++nti) {
    int p = (wv + nti * 4) * 16 + l15;
    #pragma unroll
    for (int mt = 0; mt < 4; ++mt)
      #pragma unroll
      for (int r = 0; r < 4; ++r) {
        int m = mt * 16 + quad * 4 + r;
        int jl = p - q0 + m;
        if (jl >= 0 && jl < nut)
          Eb[m * 128 + (jl ^ (((m >> 2) & 7) << 4))] = __float2bfloat16(eacc[mt][nti][r]);
      }
  }
  __syncthreads();  // s3

  // ---- S GEMM: S[80 x 160] = Aqu @ K^T ----
  const int nnt = (wv < 2) ? 3 : 2;
  float4v sacc[5][3];
  #pragma unroll
  for (int mt = 0; mt < 5; ++mt)
    #pragma unroll
    for (int i = 0; i < 3; ++i) sacc[mt][i] = (float4v){0.f, 0.f, 0.f, 0.f};
  {
    short8v au[5][2];
    #pragma unroll
    for (int mt = 0; mt < 5; ++mt)
      #pragma unroll
      for (int ks = 0; ks < 2; ++ks)
        au[mt][ks] = *(const short8v*)&Aqu[(mt * 16 + l15) * 64 + ((ks * 4 + quad) ^ key) * 8];
    #pragma unroll
    for (int nti = 0; nti < 3; ++nti) {
      if (nti < nnt) {
        int nt = wv + nti * 4;
        short8v b0 = *(const short8v*)&Kt[(nt * 16 + l15) * 64 + (quad ^ key) * 8];
        short8v b1 = *(const short8v*)&Kt[(nt * 16 + l15) * 64 + ((4 + quad) ^ key) * 8];
        #pragma unroll
        for (int mt = 0; mt < 5; ++mt) {
          sacc[mt][nti] = __builtin_amdgcn_mfma_f32_16x16x32_bf16(au[mt][0], b0, sacc[mt][nti], 0, 0, 0);
          sacc[mt][nti] = __builtin_amdgcn_mfma_f32_16x16x32_bf16(au[mt][1], b1, sacc[mt][nti], 0, 0, 0);
        }
      }
    }
  }
  __syncthreads();  // s4: Aqu/Kt dead

  // ---- assembly: + E gather, masks, scale ----
  #pragma unroll
  for (int nti = 0; nti < 3; ++nti) {
    if (nti < nnt) {
      int colv = (wv + nti * 4) * 16 + l15;
      int jl = colv - (c + 4);
      bool cvalid = (colv < ncols) && !(jl >= 0 && jl >= lenlim);
      #pragma unroll
      for (int mt = 0; mt < 5; ++mt)
        #pragma unroll
        for (int r = 0; r < 4; ++r) {
          float s = sacc[mt][nti][r];
          if (cvalid) {
            if (mt < 4 && jl >= 0) {
              int m = mt * 16 + quad * 4 + r;
              s += __bfloat162float(Eb[m * 128 + (jl ^ (((m >> 2) & 7) << 4))]);
            }
            s *= 0.125f;
          } else s = -1e30f;
          sacc[mt][nti][r] = s;
        }
    }
  }

  // ---- softmax: row max ----
  {
    #pragma unroll
    for (int mt = 0; mt < 5; ++mt)
      #pragma unroll
      for (int r = 0; r < 4; ++r) {
        float v = -3e38f;
        #pragma unroll
        for (int nti = 0; nti < 3; ++nti)
          if (nti < nnt) v = fmaxf(v, sacc[mt][nti][r]);
        v = fmaxf(v, __shfl_xor(v, 1));
        v = fmaxf(v, __shfl_xor(v, 2));
        v = fmaxf(v, __shfl_xor(v, 4));
        v = fmaxf(v, __shfl_xor(v, 8));
        if (l15 == 0) wred[(mt * 16 + quad * 4 + r) * 4 + wv] = v;
      }
  }
  __syncthreads();  // s5
  if (tid < 80)
    rstat[tid] = fmaxf(fmaxf(wred[tid * 4], wred[tid * 4 + 1]),
                       fmaxf(wred[tid * 4 + 2], wred[tid * 4 + 3]));
  __syncthreads();  // s6

  // ---- softmax: exp, write P (bf16, stride 168), row sums ----
  {
    float rmx[5][4], rsum[5][4];
    #pragma unroll
    for (int mt = 0; mt < 5; ++mt)
      #pragma unroll
      for (int r = 0; r < 4; ++r) {
        rmx[mt][r] = rstat[mt * 16 + quad * 4 + r];
        rsum[mt][r] = 0.f;
      }
    #pragma unroll
    for (int nti = 0; nti < 3; ++nti) {
      if (nti < nnt) {
        int colv = (wv + nti * 4) * 16 + l15;
        #pragma unroll
        for (int mt = 0; mt < 5; ++mt)
          #pragma unroll
          for (int r = 0; r < 4; ++r) {
            float p = __expf(sacc[mt][nti][r] - rmx[mt][r]);
            Pp[(mt * 16 + quad * 4 + r) * 168 + colv] = __float2bfloat16(p);
            rsum[mt][r] += p;
          }
      }
    }
    #pragma unroll
    for (int mt = 0; mt < 5; ++mt)
      #pragma unroll
      for (int r = 0; r < 4; ++r) {
        float v = rsum[mt][r];
        v += __shfl_xor(v, 1);
        v += __shfl_xor(v, 2);
        v += __shfl_xor(v, 4);
        v += __shfl_xor(v, 8);
        if (l15 == 0) wred[(mt * 16 + quad * 4 + r) * 4 + wv] = v;
      }
  }
  __syncthreads();  // s7
  if (tid < 80)
    rstat[tid] = 1.f / (wred[tid * 4] + wred[tid * 4 + 1] + wred[tid * 4 + 2] + wred[tid * 4 + 3]);
  __syncthreads();  // s8

  // ---- PV GEMM: O[80 x 64] = P @ V ----
  const int kmax = (ncols + 31) >> 5;
  float4v oacc[5];
  #pragma unroll
  for (int mt = 0; mt < 5; ++mt) oacc[mt] = (float4v){0.f, 0.f, 0.f, 0.f};
  const int ehi = (wv * 16 + l15) >> 3, elo = l15 & 7;
  for (int ks = 0; ks < kmax; ++ks) {
    short8v bq;
    const int blk = ehi ^ ((ks * 4 + quad) & 7);
    #pragma unroll
    for (int j = 0; j < 8; ++j)
      bq[j] = ((const short*)Vs)[(ks * 32 + quad * 8 + j) * 64 + blk * 8 + elo];
    #pragma unroll
    for (int mt = 0; mt < 5; ++mt) {
      short8v af = *(const short8v*)&Pp[(mt * 16 + l15) * 168 + ks * 32 + quad * 8];
      oacc[mt] = __builtin_amdgcn_mfma_f32_16x16x32_bf16(af, bq, oacc[mt], 0, 0, 0);
    }
  }

  // ---- epilogue: rows m<68 -> attn; m==68 (summary) -> clipped d_out ----
  #pragma unroll
  for (int mt = 0; mt < 5; ++mt) {
    #pragma unroll
    for (int r = 0; r < 4; ++r) {
      int m = mt * 16 + quad * 4 + r;
      if (m >= 69) continue;
      float o = oacc[mt][r] * rstat[m];
      if (m < 68) {
        int qrow = (m < 64) ? (64 + 64 * c + m) : (4 * c + (m - 64));
        attn[((size_t)(qrow * 8 + b)) * 512 + h * 64 + wv * 16 + l15] = __float2bfloat16(o);
      } else {
        float v = fminf(fmaxf(o, -10.f), 10.f);
        size_t oi = (size_t)1088 * 8 * 512 + ((size_t)(c * 8 + b)) * 512 + h * 64 + wv * 16 + l15;
        if (obf) ((bf16*)dout)[oi] = __float2bfloat16(v);
        else     ((float*)dout)[oi] = v;
      }
    }
  }
}

static inline int cdiv(int a, int b) { return (a + b - 1) / b; }

extern "C" void kernel_launch(void* const* d_in, const int* in_sizes, int n_in,
                              void* d_out, int out_size, void* d_ws, size_t ws_size,
                              hipStream_t stream) {
  const void* utter = d_in[0];
  const int*  lens  = (const int*)d_in[1];
  const void* rctx  = d_in[2];
  const void* summ  = d_in[3];
  const void* memry = d_in[4];
  // d_in[5] attention_mask: analytic, never read
  const void* pose  = d_in[6];
  const void* W_kv  = d_in[7];
  const void* b_kv  = d_in[8];
  const void* W_q   = d_in[9];
  const void* b_q   = d_in[10];
  const void* W_out = d_in[11];
  const void* b_out = d_in[12];
  const void* W_pos = d_in[13];
  const void* pbu   = d_in[14];
  const void* pbv   = d_in[15];

  const unsigned SZ_MM = MM * BB * DD;   // 61440
  const unsigned SZ_RC = RR * BB * DD;   // 262144
  const unsigned SZ_UT = UU * BB * DD;   // 4194304
  const unsigned SZ_SM = SS * BB * DD;   // 65536
  const unsigned N_XU  = SZ_MM + SZ_RC + SZ_UT + SZ_SM;  // 4583424
  const unsigned SZ_PS = 191 * DD;       // 97792

  int*  flag = (int*)d_ws;
  bf16* base = (bf16*)((char*)d_ws + 64);
  unsigned off = 0;
  bf16* XU    = base + off; unsigned o_XU    = off; off += N_XU;
  bf16* posec = base + off; unsigned o_posec = off; off += 192 * DD;
  bf16* Wcat  = base + off; unsigned o_Wcat  = off; off += (unsigned)NU * DD;
  bf16* bcat  = base + off; unsigned o_bcat  = off; off += NU;
  bf16* Woutp = base + off; unsigned o_Wout  = off; off += DD * DD;
  bf16* boutp = base + off; unsigned o_bout  = off; off += DD;
  bf16* Wposp = base + off; unsigned o_Wpos  = off; off += DD * DD;
  bf16* pbuc  = base + off; unsigned o_pbu   = off; off += DD;
  bf16* pbvc  = base + off; unsigned o_pbv   = off; off += DD;
  bf16* qkv   = base + off; off += (unsigned)(MU + 8) * NU;  // 8952 x 1536
  bf16* pos   = base + off; off += 192 * DD;
  bf16* attn  = base + off; off += QQ * BB * DD;

  // pack descriptor (only used in the fp32-input fallback)
  PackDesc pd;
  const void* srcs[14]  = {memry, rctx, utter, summ, pose,
                           W_q, W_kv, b_q, b_kv, W_out, b_out, W_pos, pbu, pbv};
  unsigned    soffs[14] = {0, 0, 0, 0, 896u * DD, 0, 0, 0, 0, 0, 0, 0, 0, 0};
  unsigned    doffs[14] = {o_XU, o_XU + SZ_MM, o_XU + SZ_MM + SZ_RC,
                           o_XU + SZ_MM + SZ_RC + SZ_UT, o_posec,
                           o_Wcat, o_Wcat + DD * DD, o_bcat, o_bcat + DD,
                           o_Wout, o_bout, o_Wpos, o_pbu, o_pbv};
  unsigned    ns[14]    = {SZ_MM, SZ_RC, SZ_UT, SZ_SM, SZ_PS,
                           DD * DD, 2 * DD * DD, DD, 2 * DD,
                           DD * DD, DD, DD * DD, DD, DD};
  unsigned cum = 0;
  for (int i = 0; i < 14; ++i) {
    pd.src[i] = srcs[i]; pd.srcoff[i] = soffs[i]; pd.dstoff[i] = doffs[i];
    pd.cum[i] = cum; cum += ns[i] / 8;
  }
  pd.src[14] = pbv; pd.srcoff[14] = 0; pd.dstoff[14] = o_pbv;
  pd.src[15] = pbv; pd.srcoff[15] = 0; pd.dstoff[15] = o_pbv;
  pd.cum[14] = cum; pd.cum[15] = cum; pd.cum[16] = cum;
  int nchunks = (int)cum;
  pack_all<<<dim3(cdiv(nchunks, 256)), dim3(256), 0, stream>>>(pd, base, utter, flag, nchunks);

  const int BIG = 1 << 30;
  // fused QKV GEMM: union X (4 segs, zero-copy) @ [W_q;W_kv]^T -> (8952 x 1536)
  GemmP gq;
  gq.xo[0] = (const bf16*)memry; gq.xo[1] = (const bf16*)rctx;
  gq.xo[2] = (const bf16*)utter; gq.xo[3] = (const bf16*)summ;
  gq.xp[0] = XU; gq.xp[1] = XU + SZ_MM; gq.xp[2] = XU + SZ_MM + SZ_RC;
  gq.xp[3] = XU + SZ_MM + SZ_RC + SZ_UT;
  gq.xlim[0] = 120; gq.xlim[1] = 632; gq.xlim[2] = 8824; gq.xlim[3] = BIG;
  gq.xbase[0] = 0; gq.xbase[1] = 120; gq.xbase[2] = 632; gq.xbase[3] = 8824;
  gq.wo[0] = (const bf16*)W_q; gq.wo[1] = (const bf16*)W_kv;
  gq.wp[0] = Wcat; gq.wp[1] = Wcat + DD * DD;
  gq.wlim0 = 512; gq.wbase1 = 512;
  gq.bo[0] = (const bf16*)b_q; gq.bo[1] = (const bf16*)b_kv;
  gq.bp[0] = bcat; gq.bp[1] = bcat + DD;
  gq.hasbias = 1; gq.out = qkv; gq.M = MU; gq.N = NU; gq.K = DD; gq.oflag = 0;

  // pos GEMM: pose rows [896,1087) @ W_pos^T -> (191 x 512)
  GemmP gp;
  gp.xo[0] = (const bf16*)pose + (size_t)896 * DD; gp.xp[0] = posec;
  gp.xo[1] = gp.xo[0]; gp.xp[1] = posec; gp.xo[2] = gp.xo[0]; gp.xp[2] = posec;
  gp.xo[3] = gp.xo[0]; gp.xp[3] = posec;
  gp.xlim[0] = BIG; gp.xlim[1] = BIG; gp.xlim[2] = BIG; gp.xlim[3] = BIG;
  gp.xbase[0] = 0; gp.xbase[1] = 0; gp.xbase[2] = 0; gp.xbase[3] = 0;
  gp.wo[0] = (const bf16*)W_pos; gp.wo[1] = (const bf16*)W_pos;
  gp.wp[0] = Wposp; gp.wp[1] = Wposp;
  gp.wlim0 = BIG; gp.wbase1 = 0;
  gp.bo[0] = gp.bo[1] = nullptr; gp.bp[0] = gp.bp[1] = nullptr;
  gp.hasbias = 0; gp.out = pos; gp.M = 191; gp.N = DD; gp.K = DD; gp.oflag = 0;

  // grid: QKV needs (12 x 140); pos needs 3*4=12 tiles -> one extra y row
  gemm_dual<<<dim3(12, 141), dim3(256), 0, stream>>>(gq, gp, 140, flag);

  // attention: one block per (c, b, h); writes attn rows + clipped summary rows
  attn_chunk<<<dim3(1024), dim3(256), 0, stream>>>(
      qkv, pos, (const bf16*)pbu, pbuc, (const bf16*)pbv, pbvc, lens, attn, flag, d_out);

  // out_ru = attn[:1088] @ W_out^T + b_out
  GemmP go;
  go.xo[0] = attn; go.xp[0] = attn;
  go.xo[1] = attn; go.xp[1] = attn; go.xo[2] = attn; go.xp[2] = attn;
  go.xo[3] = attn; go.xp[3] = attn;
  go.xlim[0] = BIG; go.xlim[1] = BIG; go.xlim[2] = BIG; go.xlim[3] = BIG;
  go.xbase[0] = 0; go.xbase[1] = 0; go.xbase[2] = 0; go.xbase[3] = 0;
  go.wo[0] = (const bf16*)W_out; go.wo[1] = (const bf16*)W_out;
  go.wp[0] = Woutp; go.wp[1] = Woutp;
  go.wlim0 = BIG; go.wbase1 = 0;
  go.bo[0] = (const bf16*)b_out; go.bo[1] = (const bf16*)b_out;
  go.bp[0] = boutp; go.bp[1] = boutp;
  go.hasbias = 1; go.out = d_out; go.M = (RR + UU) * BB; go.N = DD; go.K = DD;
  go.oflag = 1;
  gemm_dual<<<dim3(4, 136), dim3(256), 0, stream>>>(go, go, 136, flag);
}

// Round 8
// 267.938 us; speedup vs baseline: 1.0020x; 1.0020x over previous
//
#include <hip/hip_runtime.h>
#include <hip/hip_bf16.h>

typedef __hip_bfloat16 bf16;
typedef __attribute__((ext_vector_type(8))) short short8v;   // 8 bf16 (4 VGPRs)
typedef __attribute__((ext_vector_type(4))) float float4v;   // MFMA C/D frag

// Problem constants
#define UU 1024
#define BB 8
#define DD 512
#define HH 8
#define HD 64
#define RR 64
#define SS 16
#define MM 15
#define QQ 1104   // R + U + S
#define KVL 1103  // M + R + U
#define PEL 2047
#define NU 1536   // fused QKV output width
#define MU 8952   // union rows (15+64+1024+16)*8

#define AS1 __attribute__((address_space(1)))
#define AS3 __attribute__((address_space(3)))

__device__ __forceinline__ float lo16(unsigned u) { return __uint_as_float(u << 16); }
__device__ __forceinline__ float hi16(unsigned u) { return __uint_as_float(u & 0xffff0000u); }
__device__ __forceinline__ unsigned pk2(float a, float b) {
  unsigned short x = __builtin_bit_cast(unsigned short, __float2bfloat16(a));
  unsigned short y = __builtin_bit_cast(unsigned short, __float2bfloat16(b));
  return (unsigned)x | ((unsigned)y << 16);
}

// ---- dtype detection + (fp32 fallback only) canonicalization ----
struct PackDesc {
  const void* src[16];
  unsigned int srcoff[16];
  unsigned int dstoff[16];
  unsigned int cum[17];   // cumulative 8-element chunks
};

__global__ __launch_bounds__(256) void pack_all(PackDesc d, bf16* base,
                                                const void* __restrict__ probe,
                                                int* __restrict__ flagout,
                                                int nchunks) {
  __shared__ int wsum[4];
  const unsigned short* p = (const unsigned short*)probe;
  int big = 0;
  for (int i = threadIdx.x; i < 4096; i += 256)
    big += (((p[i] >> 7) & 0xFF) >= 137) ? 1 : 0;
  #pragma unroll
  for (int off = 32; off; off >>= 1) big += __shfl_down(big, off);
  if ((threadIdx.x & 63) == 0) wsum[threadIdx.x >> 6] = big;
  __syncthreads();
  const int flag = (wsum[0] + wsum[1] + wsum[2] + wsum[3] < 16) ? 1 : 0;
  if (threadIdx.x == 0 && blockIdx.x == 0) *flagout = flag;
  if (flag) return;  // bf16 inputs: consumers read originals directly

  int g = blockIdx.x * 256 + threadIdx.x;
  if (g >= nchunks) return;
  int s = 0;
  #pragma unroll
  for (int i = 1; i < 17; ++i) s += (g >= d.cum[i]) ? 1 : 0;
  unsigned local = (g - d.cum[s]) * 8u;
  bf16* dst = base + d.dstoff[s] + local;
  const float* fp = (const float*)d.src[s] + d.srcoff[s] + local;
  uint4 o;
  o.x = pk2(fp[0], fp[1]);
  o.y = pk2(fp[2], fp[3]);
  o.z = pk2(fp[4], fp[5]);
  o.w = pk2(fp[6], fp[7]);
  *(uint4*)dst = o;
}

// ---- MFMA GEMM, 128x128 tile, BK=128, XOR-swizzled LDS, segmented inputs ----
// (round-6 tile/occupancy: 64 KB LDS, 2 blocks/CU — proven clean write-merge)
// X rows resolved through a 4-segment table (zero-copy concat); W through a
// 2-segment table; segment pointers are (orig, packed) pairs selected by *flag.
struct GemmP {
  const bf16* xo[4]; const bf16* xp[4]; int xlim[4]; int xbase[4];
  const bf16* wo[2]; const bf16* wp[2]; int wlim0; int wbase1;
  const bf16* bo[2]; const bf16* bp[2]; int hasbias;
  void* out; int M, N, K; int oflag;   // oflag: 0 always bf16, 1 dtype per flag
};

__global__ __launch_bounds__(256) void gemm_dual(GemmP g0, GemmP g1, int ysplit,
                                                 const int* __restrict__ flag) {
  __shared__ bf16 As[128 * 128];
  __shared__ bf16 Bs[128 * 128];
  const bool bf = (*flag != 0);
  GemmP g; int bm, bn;
  if ((int)blockIdx.y < ysplit) {
    g = g0; bm = blockIdx.y * 128; bn = blockIdx.x * 128;
  } else {
    g = g1;
    int nt = g1.N >> 7;
    int bi = ((int)blockIdx.y - ysplit) * gridDim.x + blockIdx.x;
    if (bi >= ((g1.M + 127) >> 7) * nt) return;
    bm = (bi / nt) * 128; bn = (bi % nt) * 128;
  }
  const bf16* xs[4];
  #pragma unroll
  for (int i = 0; i < 4; ++i) xs[i] = bf ? g.xo[i] : g.xp[i];
  const bf16* w0 = bf ? g.wo[0] : g.wp[0];
  const bf16* w1 = bf ? g.wo[1] : g.wp[1];

  const int tid = threadIdx.x;
  const int lane = tid & 63, wv = tid >> 6;
  const int wr = wv >> 1, wc = wv & 1;
  const int l4 = lane >> 4;            // row within 4-row staging group
  const int lb = lane & 15;            // 16B block within 256B row
  const int quad = lane >> 4, l15 = lane & 15;

  float4v acc[4][4] = {};

  for (int kb = 0; kb < g.K; kb += 128) {
    #pragma unroll
    for (int i = 0; i < 8; ++i) {
      int r = wv * 32 + i * 4 + l4;
      int gm = bm + r; if (gm > g.M - 1) gm = g.M - 1;
      int s = (gm >= g.xlim[0]) + (gm >= g.xlim[1]) + (gm >= g.xlim[2]);
      const bf16* src = xs[s] + (size_t)(gm - g.xbase[s]) * g.K + kb + ((lb ^ (r & 15)) * 8);
      __builtin_amdgcn_global_load_lds((const AS1 void*)src,
                                       (AS3 void*)&As[(wv * 32 + i * 4) * 128], 16, 0, 0);
    }
    #pragma unroll
    for (int i = 0; i < 8; ++i) {
      int r = wv * 32 + i * 4 + l4;
      int gn = bn + r; if (gn > g.N - 1) gn = g.N - 1;
      const bf16* src = ((gn < g.wlim0) ? w0 + (size_t)gn * g.K
                                        : w1 + (size_t)(gn - g.wbase1) * g.K)
                        + kb + ((lb ^ (r & 15)) * 8);
      __builtin_amdgcn_global_load_lds((const AS1 void*)src,
                                       (AS3 void*)&Bs[(wv * 32 + i * 4) * 128], 16, 0, 0);
    }
    __syncthreads();
    #pragma unroll
    for (int ki = 0; ki < 4; ++ki) {
      const int slot = ((ki * 4 + quad) ^ l15) * 8;
      short8v a[4], bq[4];
      #pragma unroll
      for (int t = 0; t < 4; ++t) {
        a[t]  = *(const short8v*)&As[(wr * 64 + t * 16 + l15) * 128 + slot];
        bq[t] = *(const short8v*)&Bs[(wc * 64 + t * 16 + l15) * 128 + slot];
      }
      #pragma unroll
      for (int mt = 0; mt < 4; ++mt)
        #pragma unroll
        for (int nt = 0; nt < 4; ++nt)
          acc[mt][nt] = __builtin_amdgcn_mfma_f32_16x16x32_bf16(
              a[mt], bq[nt], acc[mt][nt], 0, 0, 0);
    }
    __syncthreads();
  }

  const bool as_bf16 = g.oflag ? bf : true;
  const bf16* b0 = bf ? g.bo[0] : g.bp[0];
  const bf16* b1 = bf ? g.bo[1] : g.bp[1];
  #pragma unroll
  for (int mt = 0; mt < 4; ++mt) {
    #pragma unroll
    for (int r = 0; r < 4; ++r) {
      int gm = bm + wr * 64 + mt * 16 + quad * 4 + r;
      if (gm >= g.M) continue;
      #pragma unroll
      for (int nt = 0; nt < 4; ++nt) {
        int gn = bn + wc * 64 + nt * 16 + l15;
        float v = acc[mt][nt][r];
        if (g.hasbias)
          v += __bfloat162float((gn < g.wlim0) ? b0[gn] : b1[gn - g.wbase1]);
        size_t o = (size_t)gm * g.N + gn;
        if (as_bf16) ((bf16*)g.out)[o] = __float2bfloat16(v);
        else         ((float*)g.out)[o] = v;
      }
    }
  }
}

// ---- MFMA chunk attention: one block per (c, b, h) ----
__device__ __forceinline__ int gcol(int row, int c, int u0, int ncols) {
  if (row < c) return row;
  if (row < c + 4) return 15 + 4 * c + (row - c);
  if (row < ncols) return 79 + u0 + (row - c - 4);
  return 0;
}

__global__ __launch_bounds__(256, 2) void attn_chunk(
    const bf16* __restrict__ qkv, const bf16* __restrict__ pos,
    const bf16* __restrict__ pbu_o, const bf16* __restrict__ pbu_p,
    const bf16* __restrict__ pbv_o, const bf16* __restrict__ pbv_p,
    const int* __restrict__ lengths, bf16* __restrict__ attn,
    const int* __restrict__ flag, void* __restrict__ dout) {
  __shared__ char lds[65536];
  bf16* Vs   = (bf16*)(lds);           // [152][64]  (k>>3)-swizzled, whole life
  bf16* Aqu  = (bf16*)(lds + 19456);   // [80][64]   row&7-swizzled, whole life
  bf16* Kt   = (bf16*)(lds + 29696);   // [152][64]  row&7-swizzled, phase B
  bf16* Aqv  = (bf16*)(lds + 32768);   // [64][64]   row&7-swizzled, phase A
  bf16* Psl  = (bf16*)(lds + 40960);   // [192][64]  row&7-swizzled, phase A
  bf16* Eb   = (bf16*)(lds + 49152);   // [64][128]  bank-swizzled, phase B
  bf16* Pp   = (bf16*)(lds + 19456);   // [80][168]  softmax phase (over Aqu/Kt)
  float* wred  = (float*)(lds + 46336); // [80][4]
  float* rstat = (float*)(lds + 47616); // [80]

  const int idx = blockIdx.x;
  const int h = idx & 7, b = (idx >> 3) & 7, c = idx >> 6;
  const int u0 = c ? (c - 1) * 64 : 0;
  const int nut = c ? 128 : 64;
  const int ncols = c + 4 + nut;
  const int q0 = c ? 63 : 127;     // pos row p = q0 - m + jl
  const int tid = threadIdx.x, lane = tid & 63, wv = tid >> 6;
  const int quad = lane >> 4, l15 = lane & 15, key = l15 & 7;
  const int lenlim = lengths[b] - u0;
  const bool obf = (*flag != 0);
  const bf16* pbu = obf ? pbu_o : pbu_p;
  const bf16* pbv = obf ? pbv_o : pbv_p;

  // ---- stage V (152 rows, (k>>3)&7-swizzle) and PosSel (192 rows) ----
  {
    int lr = lane >> 3;
    int sbr = (lane & 7) ^ lr;
    for (int i = wv; i < 19; i += 4) {
      int row = i * 8 + lr;
      int g = gcol(row, c, u0, ncols);
      int sbv = (lane & 7) ^ (i & 7);
      const bf16* src = qkv + ((size_t)(g * 8 + b)) * NU + 1024 + h * 64 + sbv * 8;
      __builtin_amdgcn_global_load_lds((const AS1 void*)src, (AS3 void*)(Vs + i * 512), 16, 0, 0);
    }
    for (int i = wv; i < 24; i += 4) {
      int p = i * 8 + lr;
      const bf16* src = pos + (size_t)p * 512 + h * 64 + sbr * 8;
      __builtin_amdgcn_global_load_lds((const AS1 void*)src, (AS3 void*)(Psl + i * 512), 16, 0, 0);
    }
  }
  // ---- stage Aqu = q + pbu (80 rows), Aqv = q_utt + pbv (64 rows) ----
  for (int id = tid; id < 1152; id += 256) {
    bool isv = id >= 640;
    int lid = isv ? id - 640 : id;
    int m = lid >> 3, ec = lid & 7;
    int qrow;
    if (isv) qrow = 64 + 64 * c + m;
    else qrow = (m < 64) ? (64 + 64 * c + m)
              : (m < 68) ? (4 * c + (m - 64))
              : (m == 68) ? (1088 + c) : 0;
    const uint4 qa = *(const uint4*)(qkv + ((size_t)((qrow + 15) * 8 + b)) * NU + h * 64 + ec * 8);
    const uint4 ba = *(const uint4*)((isv ? pbv : pbu) + h * 64 + ec * 8);
    uint4 o;
    o.x = pk2(lo16(qa.x) + lo16(ba.x), hi16(qa.x) + hi16(ba.x));
    o.y = pk2(lo16(qa.y) + lo16(ba.y), hi16(qa.y) + hi16(ba.y));
    o.z = pk2(lo16(qa.z) + lo16(ba.z), hi16(qa.z) + hi16(ba.z));
    o.w = pk2(lo16(qa.w) + lo16(ba.w), hi16(qa.w) + hi16(ba.w));
    *(uint4*)((isv ? Aqv : Aqu) + m * 64 + (ec ^ (m & 7)) * 8) = o;
  }
  __syncthreads();  // s1

  // ---- E GEMM: E[64 x 192] = Aqv @ PosSel^T ----
  float4v eacc[4][3];
  #pragma unroll
  for (int mt = 0; mt < 4; ++mt)
    #pragma unroll
    for (int i = 0; i < 3; ++i) eacc[mt][i] = (float4v){0.f, 0.f, 0.f, 0.f};
  {
    short8v av[4][2];
    #pragma unroll
    for (int mt = 0; mt < 4; ++mt)
      #pragma unroll
      for (int ks = 0; ks < 2; ++ks)
        av[mt][ks] = *(const short8v*)&Aqv[(mt * 16 + l15) * 64 + ((ks * 4 + quad) ^ key) * 8];
    #pragma unroll
    for (int nti = 0; nti < 3; ++nti) {
      int nt = wv + nti * 4;
      short8v b0 = *(const short8v*)&Psl[(nt * 16 + l15) * 64 + (quad ^ key) * 8];
      short8v b1 = *(const short8v*)&Psl[(nt * 16 + l15) * 64 + ((4 + quad) ^ key) * 8];
      #pragma unroll
      for (int mt = 0; mt < 4; ++mt) {
        eacc[mt][nti] = __builtin_amdgcn_mfma_f32_16x16x32_bf16(av[mt][0], b0, eacc[mt][nti], 0, 0, 0);
        eacc[mt][nti] = __builtin_amdgcn_mfma_f32_16x16x32_bf16(av[mt][1], b1, eacc[mt][nti], 0, 0, 0);
      }
    }
  }
  __syncthreads();  // s2: Aqv/Psl dead

  // ---- stage K (row&7-swizzle) + scatter E into Eb (bank-swizzled) ----
  {
    int lr = lane >> 3, sbr = (lane & 7) ^ lr;
    for (int i = wv; i < 19; i += 4) {
      int row = i * 8 + lr;
      int g = gcol(row, c, u0, ncols);
      const bf16* src = qkv + ((size_t)(g * 8 + b)) * NU + 512 + h * 64 + sbr * 8;
      __builtin_amdgcn_global_load_lds((const AS1 void*)src, (AS3 void*)(Kt + i * 512), 16, 0, 0);
    }
  }
  #pragma unroll
  for (int nti = 0; nti < 3; ++nti) {
    int p = (wv + nti * 4) * 16 + l15;
    #pragma unroll
    for (int mt = 0; mt < 4; ++mt)
      #pragma unroll
      for (int r = 0; r < 4; ++r) {
        int m = mt * 16 + quad * 4 + r;
        int jl = p - q0 + m;
        if (jl >= 0 && jl < nut)
          Eb[m * 128 + (jl ^ (((m >> 2) & 7) << 4))] = __float2bfloat16(eacc[mt][nti][r]);
      }
  }
  __syncthreads();  // s3

  // ---- S GEMM: S[80 x 160] = Aqu @ K^T ----
  const int nnt = (wv < 2) ? 3 : 2;
  float4v sacc[5][3];
  #pragma unroll
  for (int mt = 0; mt < 5; ++mt)
    #pragma unroll
    for (int i = 0; i < 3; ++i) sacc[mt][i] = (float4v){0.f, 0.f, 0.f, 0.f};
  {
    short8v au[5][2];
    #pragma unroll
    for (int mt = 0; mt < 5; ++mt)
      #pragma unroll
      for (int ks = 0; ks < 2; ++ks)
        au[mt][ks] = *(const short8v*)&Aqu[(mt * 16 + l15) * 64 + ((ks * 4 + quad) ^ key) * 8];
    #pragma unroll
    for (int nti = 0; nti < 3; ++nti) {
      if (nti < nnt) {
        int nt = wv + nti * 4;
        short8v b0 = *(const short8v*)&Kt[(nt * 16 + l15) * 64 + (quad ^ key) * 8];
        short8v b1 = *(const short8v*)&Kt[(nt * 16 + l15) * 64 + ((4 + quad) ^ key) * 8];
        #pragma unroll
        for (int mt = 0; mt < 5; ++mt) {
          sacc[mt][nti] = __builtin_amdgcn_mfma_f32_16x16x32_bf16(au[mt][0], b0, sacc[mt][nti], 0, 0, 0);
          sacc[mt][nti] = __builtin_amdgcn_mfma_f32_16x16x32_bf16(au[mt][1], b1, sacc[mt][nti], 0, 0, 0);
        }
      }
    }
  }
  __syncthreads();  // s4: Aqu/Kt dead

  // ---- assembly: + E gather, masks, scale ----
  #pragma unroll
  for (int nti = 0; nti < 3; ++nti) {
    if (nti < nnt) {
      int colv = (wv + nti * 4) * 16 + l15;
      int jl = colv - (c + 4);
      bool cvalid = (colv < ncols) && !(jl >= 0 && jl >= lenlim);
      #pragma unroll
      for (int mt = 0; mt < 5; ++mt)
        #pragma unroll
        for (int r = 0; r < 4; ++r) {
          float s = sacc[mt][nti][r];
          if (cvalid) {
            if (mt < 4 && jl >= 0) {
              int m = mt * 16 + quad * 4 + r;
              s += __bfloat162float(Eb[m * 128 + (jl ^ (((m >> 2) & 7) << 4))]);
            }
            s *= 0.125f;
          } else s = -1e30f;
          sacc[mt][nti][r] = s;
        }
    }
  }

  // ---- softmax: row max ----
  {
    #pragma unroll
    for (int mt = 0; mt < 5; ++mt)
      #pragma unroll
      for (int r = 0; r < 4; ++r) {
        float v = -3e38f;
        #pragma unroll
        for (int nti = 0; nti < 3; ++nti)
          if (nti < nnt) v = fmaxf(v, sacc[mt][nti][r]);
        v = fmaxf(v, __shfl_xor(v, 1));
        v = fmaxf(v, __shfl_xor(v, 2));
        v = fmaxf(v, __shfl_xor(v, 4));
        v = fmaxf(v, __shfl_xor(v, 8));
        if (l15 == 0) wred[(mt * 16 + quad * 4 + r) * 4 + wv] = v;
      }
  }
  __syncthreads();  // s5
  if (tid < 80)
    rstat[tid] = fmaxf(fmaxf(wred[tid * 4], wred[tid * 4 + 1]),
                       fmaxf(wred[tid * 4 + 2], wred[tid * 4 + 3]));
  __syncthreads();  // s6

  // ---- softmax: exp, write P (bf16, stride 168), row sums ----
  {
    float rmx[5][4], rsum[5][4];
    #pragma unroll
    for (int mt = 0; mt < 5; ++mt)
      #pragma unroll
      for (int r = 0; r < 4; ++r) {
        rmx[mt][r] = rstat[mt * 16 + quad * 4 + r];
        rsum[mt][r] = 0.f;
      }
    #pragma unroll
    for (int nti = 0; nti < 3; ++nti) {
      if (nti < nnt) {
        int colv = (wv + nti * 4) * 16 + l15;
        #pragma unroll
        for (int mt = 0; mt < 5; ++mt)
          #pragma unroll
          for (int r = 0; r < 4; ++r) {
            float p = __expf(sacc[mt][nti][r] - rmx[mt][r]);
            Pp[(mt * 16 + quad * 4 + r) * 168 + colv] = __float2bfloat16(p);
            rsum[mt][r] += p;
          }
      }
    }
    #pragma unroll
    for (int mt = 0; mt < 5; ++mt)
      #pragma unroll
      for (int r = 0; r < 4; ++r) {
        float v = rsum[mt][r];
        v += __shfl_xor(v, 1);
        v += __shfl_xor(v, 2);
        v += __shfl_xor(v, 4);
        v += __shfl_xor(v, 8);
        if (l15 == 0) wred[(mt * 16 + quad * 4 + r) * 4 + wv] = v;
      }
  }
  __syncthreads();  // s7
  if (tid < 80)
    rstat[tid] = 1.f / (wred[tid * 4] + wred[tid * 4 + 1] + wred[tid * 4 + 2] + wred[tid * 4 + 3]);
  __syncthreads();  // s8

  // ---- PV GEMM: O[80 x 64] = P @ V ----
  const int kmax = (ncols + 31) >> 5;
  float4v oacc[5];
  #pragma unroll
  for (int mt = 0; mt < 5; ++mt) oacc[mt] = (float4v){0.f, 0.f, 0.f, 0.f};
  const int ehi = (wv * 16 + l15) >> 3, elo = l15 & 7;
  for (int ks = 0; ks < kmax; ++ks) {
    short8v bq;
    const int blk = ehi ^ ((ks * 4 + quad) & 7);
    #pragma unroll
    for (int j = 0; j < 8; ++j)
      bq[j] = ((const short*)Vs)[(ks * 32 + quad * 8 + j) * 64 + blk * 8 + elo];
    #pragma unroll
    for (int mt = 0; mt < 5; ++mt) {
      short8v af = *(const short8v*)&Pp[(mt * 16 + l15) * 168 + ks * 32 + quad * 8];
      oacc[mt] = __builtin_amdgcn_mfma_f32_16x16x32_bf16(af, bq, oacc[mt], 0, 0, 0);
    }
  }

  // ---- epilogue: rows m<68 -> attn; m==68 (summary) -> clipped d_out ----
  #pragma unroll
  for (int mt = 0; mt < 5; ++mt) {
    #pragma unroll
    for (int r = 0; r < 4; ++r) {
      int m = mt * 16 + quad * 4 + r;
      if (m >= 69) continue;
      float o = oacc[mt][r] * rstat[m];
      if (m < 68) {
        int qrow = (m < 64) ? (64 + 64 * c + m) : (4 * c + (m - 64));
        attn[((size_t)(qrow * 8 + b)) * 512 + h * 64 + wv * 16 + l15] = __float2bfloat16(o);
      } else {
        float v = fminf(fmaxf(o, -10.f), 10.f);
        size_t oi = (size_t)1088 * 8 * 512 + ((size_t)(c * 8 + b)) * 512 + h * 64 + wv * 16 + l15;
        if (obf) ((bf16*)dout)[oi] = __float2bfloat16(v);
        else     ((float*)dout)[oi] = v;
      }
    }
  }
}

static inline int cdiv(int a, int b) { return (a + b - 1) / b; }

extern "C" void kernel_launch(void* const* d_in, const int* in_sizes, int n_in,
                              void* d_out, int out_size, void* d_ws, size_t ws_size,
                              hipStream_t stream) {
  const void* utter = d_in[0];
  const int*  lens  = (const int*)d_in[1];
  const void* rctx  = d_in[2];
  const void* summ  = d_in[3];
  const void* memry = d_in[4];
  // d_in[5] attention_mask: analytic, never read
  const void* pose  = d_in[6];
  const void* W_kv  = d_in[7];
  const void* b_kv  = d_in[8];
  const void* W_q   = d_in[9];
  const void* b_q   = d_in[10];
  const void* W_out = d_in[11];
  const void* b_out = d_in[12];
  const void* W_pos = d_in[13];
  const void* pbu   = d_in[14];
  const void* pbv   = d_in[15];

  const unsigned SZ_MM = MM * BB * DD;   // 61440
  const unsigned SZ_RC = RR * BB * DD;   // 262144
  const unsigned SZ_UT = UU * BB * DD;   // 4194304
  const unsigned SZ_SM = SS * BB * DD;   // 65536
  const unsigned N_XU  = SZ_MM + SZ_RC + SZ_UT + SZ_SM;  // 4583424
  const unsigned SZ_PS = 191 * DD;       // 97792

  int*  flag = (int*)d_ws;
  bf16* base = (bf16*)((char*)d_ws + 64);
  unsigned off = 0;
  bf16* XU    = base + off; unsigned o_XU    = off; off += N_XU;
  bf16* posec = base + off; unsigned o_posec = off; off += 192 * DD;
  bf16* Wcat  = base + off; unsigned o_Wcat  = off; off += (unsigned)NU * DD;
  bf16* bcat  = base + off; unsigned o_bcat  = off; off += NU;
  bf16* Woutp = base + off; unsigned o_Wout  = off; off += DD * DD;
  bf16* boutp = base + off; unsigned o_bout  = off; off += DD;
  bf16* Wposp = base + off; unsigned o_Wpos  = off; off += DD * DD;
  bf16* pbuc  = base + off; unsigned o_pbu   = off; off += DD;
  bf16* pbvc  = base + off; unsigned o_pbv   = off; off += DD;
  bf16* qkv   = base + off; off += (unsigned)(MU + 8) * NU;  // 8960 x 1536
  bf16* pos   = base + off; off += 192 * DD;
  bf16* attn  = base + off; off += QQ * BB * DD;

  // pack descriptor (only used in the fp32-input fallback)
  PackDesc pd;
  const void* srcs[14]  = {memry, rctx, utter, summ, pose,
                           W_q, W_kv, b_q, b_kv, W_out, b_out, W_pos, pbu, pbv};
  unsigned    soffs[14] = {0, 0, 0, 0, 896u * DD, 0, 0, 0, 0, 0, 0, 0, 0, 0};
  unsigned    doffs[14] = {o_XU, o_XU + SZ_MM, o_XU + SZ_MM + SZ_RC,
                           o_XU + SZ_MM + SZ_RC + SZ_UT, o_posec,
                           o_Wcat, o_Wcat + DD * DD, o_bcat, o_bcat + DD,
                           o_Wout, o_bout, o_Wpos, o_pbu, o_pbv};
  unsigned    ns[14]    = {SZ_MM, SZ_RC, SZ_UT, SZ_SM, SZ_PS,
                           DD * DD, 2 * DD * DD, DD, 2 * DD,
                           DD * DD, DD, DD * DD, DD, DD};
  unsigned cum = 0;
  for (int i = 0; i < 14; ++i) {
    pd.src[i] = srcs[i]; pd.srcoff[i] = soffs[i]; pd.dstoff[i] = doffs[i];
    pd.cum[i] = cum; cum += ns[i] / 8;
  }
  pd.src[14] = pbv; pd.srcoff[14] = 0; pd.dstoff[14] = o_pbv;
  pd.src[15] = pbv; pd.srcoff[15] = 0; pd.dstoff[15] = o_pbv;
  pd.cum[14] = cum; pd.cum[15] = cum; pd.cum[16] = cum;
  int nchunks = (int)cum;
  pack_all<<<dim3(cdiv(nchunks, 256)), dim3(256), 0, stream>>>(pd, base, utter, flag, nchunks);

  const int BIG = 1 << 30;
  // fused QKV GEMM: union X (4 segs, zero-copy) @ [W_q;W_kv]^T -> (8952 x 1536)
  GemmP gq;
  gq.xo[0] = (const bf16*)memry; gq.xo[1] = (const bf16*)rctx;
  gq.xo[2] = (const bf16*)utter; gq.xo[3] = (const bf16*)summ;
  gq.xp[0] = XU; gq.xp[1] = XU + SZ_MM; gq.xp[2] = XU + SZ_MM + SZ_RC;
  gq.xp[3] = XU + SZ_MM + SZ_RC + SZ_UT;
  gq.xlim[0] = 120; gq.xlim[1] = 632; gq.xlim[2] = 8824; gq.xlim[3] = BIG;
  gq.xbase[0] = 0; gq.xbase[1] = 120; gq.xbase[2] = 632; gq.xbase[3] = 8824;
  gq.wo[0] = (const bf16*)W_q; gq.wo[1] = (const bf16*)W_kv;
  gq.wp[0] = Wcat; gq.wp[1] = Wcat + DD * DD;
  gq.wlim0 = 512; gq.wbase1 = 512;
  gq.bo[0] = (const bf16*)b_q; gq.bo[1] = (const bf16*)b_kv;
  gq.bp[0] = bcat; gq.bp[1] = bcat + DD;
  gq.hasbias = 1; gq.out = qkv; gq.M = MU; gq.N = NU; gq.K = DD; gq.oflag = 0;

  // pos GEMM: pose rows [896,1087) @ W_pos^T -> (191 x 512)
  GemmP gp;
  gp.xo[0] = (const bf16*)pose + (size_t)896 * DD; gp.xp[0] = posec;
  gp.xo[1] = gp.xo[0]; gp.xp[1] = posec; gp.xo[2] = gp.xo[0]; gp.xp[2] = posec;
  gp.xo[3] = gp.xo[0]; gp.xp[3] = posec;
  gp.xlim[0] = BIG; gp.xlim[1] = BIG; gp.xlim[2] = BIG; gp.xlim[3] = BIG;
  gp.xbase[0] = 0; gp.xbase[1] = 0; gp.xbase[2] = 0; gp.xbase[3] = 0;
  gp.wo[0] = (const bf16*)W_pos; gp.wo[1] = (const bf16*)W_pos;
  gp.wp[0] = Wposp; gp.wp[1] = Wposp;
  gp.wlim0 = BIG; gp.wbase1 = 0;
  gp.bo[0] = gp.bo[1] = nullptr; gp.bp[0] = gp.bp[1] = nullptr;
  gp.hasbias = 0; gp.out = pos; gp.M = 191; gp.N = DD; gp.K = DD; gp.oflag = 0;

  // grid: QKV needs (12 x 70) 128-tiles; pos needs 2*4=8 -> one extra y row
  gemm_dual<<<dim3(12, 71), dim3(256), 0, stream>>>(gq, gp, 70, flag);

  // attention: one block per (c, b, h); writes attn rows + clipped summary rows
  attn_chunk<<<dim3(1024), dim3(256), 0, stream>>>(
      qkv, pos, (const bf16*)pbu, pbuc, (const bf16*)pbv, pbvc, lens, attn, flag, d_out);

  // out_ru = attn[:1088] @ W_out^T + b_out
  GemmP go;
  go.xo[0] = attn; go.xp[0] = attn;
  go.xo[1] = attn; go.xp[1] = attn; go.xo[2] = attn; go.xp[2] = attn;
  go.xo[3] = attn; go.xp[3] = attn;
  go.xlim[0] = BIG; go.xlim[1] = BIG; go.xlim[2] = BIG; go.xlim[3] = BIG;
  go.xbase[0] = 0; go.xbase[1] = 0; go.xbase[2] = 0; go.xbase[3] = 0;
  go.wo[0] = (const bf16*)W_out; go.wo[1] = (const bf16*)W_out;
  go.wp[0] = Woutp; go.wp[1] = Woutp;
  go.wlim0 = BIG; go.wbase1 = 0;
  go.bo[0] = (const bf16*)b_out; go.bo[1] = (const bf16*)b_out;
  go.bp[0] = boutp; go.bp[1] = boutp;
  go.hasbias = 1; go.out = d_out; go.M = (RR + UU) * BB; go.N = DD; go.K = DD;
  go.oflag = 1;
  gemm_dual<<<dim3(4, 68), dim3(256), 0, stream>>>(go, go, 68, flag);
}

// Round 9
// 212.464 us; speedup vs baseline: 1.2636x; 1.2611x over previous
//
#include <hip/hip_runtime.h>
#include <hip/hip_bf16.h>

typedef __hip_bfloat16 bf16;
typedef __attribute__((ext_vector_type(8))) short short8v;   // 8 bf16 (4 VGPRs)
typedef __attribute__((ext_vector_type(4))) float float4v;   // MFMA C/D frag

// Problem constants
#define UU 1024
#define BB 8
#define DD 512
#define HH 8
#define HD 64
#define RR 64
#define SS 16
#define MM 15
#define QQ 1104   // R + U + S
#define KVL 1103  // M + R + U
#define PEL 2047
#define NU 1536   // fused QKV output width
#define MU 8952   // union rows (15+64+1024+16)*8

#define AS1 __attribute__((address_space(1)))
#define AS3 __attribute__((address_space(3)))

__device__ __forceinline__ float lo16(unsigned u) { return __uint_as_float(u << 16); }
__device__ __forceinline__ float hi16(unsigned u) { return __uint_as_float(u & 0xffff0000u); }
__device__ __forceinline__ unsigned pk2(float a, float b) {
  unsigned short x = __builtin_bit_cast(unsigned short, __float2bfloat16(a));
  unsigned short y = __builtin_bit_cast(unsigned short, __float2bfloat16(b));
  return (unsigned)x | ((unsigned)y << 16);
}

// ---- fused canonicalization + in-block dtype detection ----
// NOTE: always copies into workspace (even for bf16). Measured (r6 vs r8):
// the copy acts as L2 prefetch + poison-flush absorber; zero-copy regressed
// the downstream GEMM by +35 us (WRITE_SIZE 27->70 MB).
struct PackDesc {
  const void* src[16];
  unsigned int srcoff[16];
  unsigned int dstoff[16];
  unsigned int cum[17];   // cumulative 8-element chunks
};

__global__ __launch_bounds__(256) void pack_all(PackDesc d, bf16* base,
                                                const void* __restrict__ probe,
                                                int* __restrict__ flagout,
                                                int nchunks) {
  __shared__ int wsum[4];
  const unsigned short* p = (const unsigned short*)probe;
  int big = 0;
  for (int i = threadIdx.x; i < 4096; i += 256)
    big += (((p[i] >> 7) & 0xFF) >= 137) ? 1 : 0;
  #pragma unroll
  for (int off = 32; off; off >>= 1) big += __shfl_down(big, off);
  if ((threadIdx.x & 63) == 0) wsum[threadIdx.x >> 6] = big;
  __syncthreads();
  const int flag = (wsum[0] + wsum[1] + wsum[2] + wsum[3] < 16) ? 1 : 0;
  if (threadIdx.x == 0 && blockIdx.x == 0) *flagout = flag;

  int g = blockIdx.x * 256 + threadIdx.x;
  if (g >= nchunks) return;
  int s = 0;
  #pragma unroll
  for (int i = 1; i < 17; ++i) s += (g >= d.cum[i]) ? 1 : 0;
  unsigned local = (g - d.cum[s]) * 8u;
  bf16* dst = base + d.dstoff[s] + local;
  if (flag) {
    const uint4 v = *(const uint4*)((const bf16*)d.src[s] + d.srcoff[s] + local);
    *(uint4*)dst = v;
  } else {
    const float* fp = (const float*)d.src[s] + d.srcoff[s] + local;
    uint4 o;
    o.x = pk2(fp[0], fp[1]);
    o.y = pk2(fp[2], fp[3]);
    o.z = pk2(fp[4], fp[5]);
    o.w = pk2(fp[6], fp[7]);
    *(uint4*)dst = o;
  }
}

// ---- MFMA GEMM, 128x128 tile, BK=128, XOR-swizzled LDS ----
// g0 tiles are XCD-swizzled: linear block id bi -> xcd = bi&7 sweeps all
// N-tiles of M-tile (bi&7)+8*((bi>>3)/nbn), so each A-tile lives in exactly
// one XCD's L2 (dispatch round-robin assumption; perf-only heuristic).
struct GemmP {
  const bf16* X; const bf16* W; const bf16* bias; void* out;
  int M, N, K; const int* outf;
};

__global__ __launch_bounds__(256) void gemm_dual(GemmP g0, GemmP g1, int ysplit) {
  __shared__ bf16 As[128 * 128];
  __shared__ bf16 Bs[128 * 128];
  GemmP g; int bm, bn;
  if ((int)blockIdx.y < ysplit) {
    g = g0;
    int bi = (int)blockIdx.y * (int)gridDim.x + (int)blockIdx.x;
    int nbn = g0.N >> 7;
    int j = bi >> 3;
    int bmi = (bi & 7) + (j / nbn) * 8;
    int bni = j % nbn;
    if (bmi >= ((g0.M + 127) >> 7)) return;
    bm = bmi * 128; bn = bni * 128;
  } else {
    g = g1;
    int nt = g1.N >> 7;
    int bi = ((int)blockIdx.y - ysplit) * gridDim.x + blockIdx.x;
    if (bi >= ((g1.M + 127) >> 7) * nt) return;
    bm = (bi / nt) * 128; bn = (bi % nt) * 128;
  }
  const int tid = threadIdx.x;
  const int lane = tid & 63, wv = tid >> 6;
  const int wr = wv >> 1, wc = wv & 1;
  const int l4 = lane >> 4;            // row within 4-row staging group
  const int lb = lane & 15;            // 16B block within 256B row
  const int quad = lane >> 4, l15 = lane & 15;

  float4v acc[4][4] = {};

  for (int kb = 0; kb < g.K; kb += 128) {
    #pragma unroll
    for (int i = 0; i < 8; ++i) {
      int r = wv * 32 + i * 4 + l4;
      int gm = bm + r; if (gm > g.M - 1) gm = g.M - 1;
      const bf16* src = g.X + (size_t)gm * g.K + kb + ((lb ^ (r & 15)) * 8);
      __builtin_amdgcn_global_load_lds((const AS1 void*)src,
                                       (AS3 void*)&As[(wv * 32 + i * 4) * 128], 16, 0, 0);
    }
    #pragma unroll
    for (int i = 0; i < 8; ++i) {
      int r = wv * 32 + i * 4 + l4;
      int gn = bn + r; if (gn > g.N - 1) gn = g.N - 1;
      const bf16* src = g.W + (size_t)gn * g.K + kb + ((lb ^ (r & 15)) * 8);
      __builtin_amdgcn_global_load_lds((const AS1 void*)src,
                                       (AS3 void*)&Bs[(wv * 32 + i * 4) * 128], 16, 0, 0);
    }
    __syncthreads();
    #pragma unroll
    for (int ki = 0; ki < 4; ++ki) {
      const int slot = ((ki * 4 + quad) ^ l15) * 8;
      short8v a[4], bq[4];
      #pragma unroll
      for (int t = 0; t < 4; ++t) {
        a[t]  = *(const short8v*)&As[(wr * 64 + t * 16 + l15) * 128 + slot];
        bq[t] = *(const short8v*)&Bs[(wc * 64 + t * 16 + l15) * 128 + slot];
      }
      #pragma unroll
      for (int mt = 0; mt < 4; ++mt)
        #pragma unroll
        for (int nt = 0; nt < 4; ++nt)
          acc[mt][nt] = __builtin_amdgcn_mfma_f32_16x16x32_bf16(
              a[mt], bq[nt], acc[mt][nt], 0, 0, 0);
    }
    __syncthreads();
  }

  const bool as_bf16 = (g.outf == nullptr) ? true : (*g.outf != 0);
  #pragma unroll
  for (int mt = 0; mt < 4; ++mt) {
    #pragma unroll
    for (int r = 0; r < 4; ++r) {
      int gm = bm + wr * 64 + mt * 16 + quad * 4 + r;
      if (gm >= g.M) continue;
      #pragma unroll
      for (int nt = 0; nt < 4; ++nt) {
        int gn = bn + wc * 64 + nt * 16 + l15;
        float v = acc[mt][nt][r];
        if (g.bias) v += __bfloat162float(g.bias[gn]);
        size_t o = (size_t)gm * g.N + gn;
        if (as_bf16) ((bf16*)g.out)[o] = __float2bfloat16(v);
        else         ((float*)g.out)[o] = v;
      }
    }
  }
}

// ---- MFMA chunk attention: one block per (c, b, h) ----
__device__ __forceinline__ int gcol(int row, int c, int u0, int ncols) {
  if (row < c) return row;
  if (row < c + 4) return 15 + 4 * c + (row - c);
  if (row < ncols) return 79 + u0 + (row - c - 4);
  return 0;
}

__global__ __launch_bounds__(256, 2) void attn_chunk(
    const bf16* __restrict__ qkv, const bf16* __restrict__ pos,
    const bf16* __restrict__ pbu, const bf16* __restrict__ pbv,
    const int* __restrict__ lengths, bf16* __restrict__ attn,
    const int* __restrict__ flag, void* __restrict__ dout) {
  __shared__ char lds[65536];
  bf16* Vs   = (bf16*)(lds);           // [152][64]  (k>>3)-swizzled, whole life
  bf16* Aqu  = (bf16*)(lds + 19456);   // [80][64]   row&7-swizzled, whole life
  bf16* Kt   = (bf16*)(lds + 29696);   // [152][64]  row&7-swizzled, phase B
  bf16* Aqv  = (bf16*)(lds + 32768);   // [64][64]   row&7-swizzled, phase A
  bf16* Psl  = (bf16*)(lds + 40960);   // [192][64]  row&7-swizzled, phase A
  bf16* Eb   = (bf16*)(lds + 49152);   // [64][128]  bank-swizzled, phase B
  bf16* Pp   = (bf16*)(lds + 19456);   // [80][168]  softmax phase (over Aqu/Kt)
  float* wred  = (float*)(lds + 46336); // [80][4]
  float* rstat = (float*)(lds + 47616); // [80]

  const int idx = blockIdx.x;
  const int h = idx & 7, b = (idx >> 3) & 7, c = idx >> 6;
  const int u0 = c ? (c - 1) * 64 : 0;
  const int nut = c ? 128 : 64;
  const int ncols = c + 4 + nut;
  const int q0 = c ? 63 : 127;     // pos row p = q0 - m + jl
  const int tid = threadIdx.x, lane = tid & 63, wv = tid >> 6;
  const int quad = lane >> 4, l15 = lane & 15, key = l15 & 7;
  const int lenlim = lengths[b] - u0;
  const bool obf = (*flag != 0);

  // ---- stage V (152 rows, (k>>3)&7-swizzle) and PosSel (192 rows) ----
  {
    int lr = lane >> 3;
    int sbr = (lane & 7) ^ lr;
    for (int i = wv; i < 19; i += 4) {
      int row = i * 8 + lr;
      int g = gcol(row, c, u0, ncols);
      int sbv = (lane & 7) ^ (i & 7);
      const bf16* src = qkv + ((size_t)(g * 8 + b)) * NU + 1024 + h * 64 + sbv * 8;
      __builtin_amdgcn_global_load_lds((const AS1 void*)src, (AS3 void*)(Vs + i * 512), 16, 0, 0);
    }
    for (int i = wv; i < 24; i += 4) {
      int p = i * 8 + lr;
      const bf16* src = pos + (size_t)p * 512 + h * 64 + sbr * 8;
      __builtin_amdgcn_global_load_lds((const AS1 void*)src, (AS3 void*)(Psl + i * 512), 16, 0, 0);
    }
  }
  // ---- stage Aqu = q + pbu (80 rows), Aqv = q_utt + pbv (64 rows) ----
  for (int id = tid; id < 1152; id += 256) {
    bool isv = id >= 640;
    int lid = isv ? id - 640 : id;
    int m = lid >> 3, ec = lid & 7;
    int qrow;
    if (isv) qrow = 64 + 64 * c + m;
    else qrow = (m < 64) ? (64 + 64 * c + m)
              : (m < 68) ? (4 * c + (m - 64))
              : (m == 68) ? (1088 + c) : 0;
    const uint4 qa = *(const uint4*)(qkv + ((size_t)((qrow + 15) * 8 + b)) * NU + h * 64 + ec * 8);
    const uint4 ba = *(const uint4*)((isv ? pbv : pbu) + h * 64 + ec * 8);
    uint4 o;
    o.x = pk2(lo16(qa.x) + lo16(ba.x), hi16(qa.x) + hi16(ba.x));
    o.y = pk2(lo16(qa.y) + lo16(ba.y), hi16(qa.y) + hi16(ba.y));
    o.z = pk2(lo16(qa.z) + lo16(ba.z), hi16(qa.z) + hi16(ba.z));
    o.w = pk2(lo16(qa.w) + lo16(ba.w), hi16(qa.w) + hi16(ba.w));
    *(uint4*)((isv ? Aqv : Aqu) + m * 64 + (ec ^ (m & 7)) * 8) = o;
  }
  __syncthreads();  // s1

  // ---- E GEMM: E[64 x 192] = Aqv @ PosSel^T ----
  float4v eacc[4][3];
  #pragma unroll
  for (int mt = 0; mt < 4; ++mt)
    #pragma unroll
    for (int i = 0; i < 3; ++i) eacc[mt][i] = (float4v){0.f, 0.f, 0.f, 0.f};
  {
    short8v av[4][2];
    #pragma unroll
    for (int mt = 0; mt < 4; ++mt)
      #pragma unroll
      for (int ks = 0; ks < 2; ++ks)
        av[mt][ks] = *(const short8v*)&Aqv[(mt * 16 + l15) * 64 + ((ks * 4 + quad) ^ key) * 8];
    #pragma unroll
    for (int nti = 0; nti < 3; ++nti) {
      int nt = wv + nti * 4;
      short8v b0 = *(const short8v*)&Psl[(nt * 16 + l15) * 64 + (quad ^ key) * 8];
      short8v b1 = *(const short8v*)&Psl[(nt * 16 + l15) * 64 + ((4 + quad) ^ key) * 8];
      #pragma unroll
      for (int mt = 0; mt < 4; ++mt) {
        eacc[mt][nti] = __builtin_amdgcn_mfma_f32_16x16x32_bf16(av[mt][0], b0, eacc[mt][nti], 0, 0, 0);
        eacc[mt][nti] = __builtin_amdgcn_mfma_f32_16x16x32_bf16(av[mt][1], b1, eacc[mt][nti], 0, 0, 0);
      }
    }
  }
  __syncthreads();  // s2: Aqv/Psl dead

  // ---- stage K (row&7-swizzle) + scatter E into Eb (bank-swizzled) ----
  {
    int lr = lane >> 3, sbr = (lane & 7) ^ lr;
    for (int i = wv; i < 19; i += 4) {
      int row = i * 8 + lr;
      int g = gcol(row, c, u0, ncols);
      const bf16* src = qkv + ((size_t)(g * 8 + b)) * NU + 512 + h * 64 + sbr * 8;
      __builtin_amdgcn_global_load_lds((const AS1 void*)src, (AS3 void*)(Kt + i * 512), 16, 0, 0);
    }
  }
  #pragma unroll
  for (int nti = 0; nti < 3; ++nti) {
    int p = (wv + nti * 4) * 16 + l15;
    #pragma unroll
    for (int mt = 0; mt < 4; ++mt)
      #pragma unroll
      for (int r = 0; r < 4; ++r) {
        int m = mt * 16 + quad * 4 + r;
        int jl = p - q0 + m;
        if (jl >= 0 && jl < nut)
          Eb[m * 128 + (jl ^ (((m >> 2) & 7) << 4))] = __float2bfloat16(eacc[mt][nti][r]);
      }
  }
  __syncthreads();  // s3

  // ---- S GEMM: S[80 x 160] = Aqu @ K^T ----
  const int nnt = (wv < 2) ? 3 : 2;
  float4v sacc[5][3];
  #pragma unroll
  for (int mt = 0; mt < 5; ++mt)
    #pragma unroll
    for (int i = 0; i < 3; ++i) sacc[mt][i] = (float4v){0.f, 0.f, 0.f, 0.f};
  {
    short8v au[5][2];
    #pragma unroll
    for (int mt = 0; mt < 5; ++mt)
      #pragma unroll
      for (int ks = 0; ks < 2; ++ks)
        au[mt][ks] = *(const short8v*)&Aqu[(mt * 16 + l15) * 64 + ((ks * 4 + quad) ^ key) * 8];
    #pragma unroll
    for (int nti = 0; nti < 3; ++nti) {
      if (nti < nnt) {
        int nt = wv + nti * 4;
        short8v b0 = *(const short8v*)&Kt[(nt * 16 + l15) * 64 + (quad ^ key) * 8];
        short8v b1 = *(const short8v*)&Kt[(nt * 16 + l15) * 64 + ((4 + quad) ^ key) * 8];
        #pragma unroll
        for (int mt = 0; mt < 5; ++mt) {
          sacc[mt][nti] = __builtin_amdgcn_mfma_f32_16x16x32_bf16(au[mt][0], b0, sacc[mt][nti], 0, 0, 0);
          sacc[mt][nti] = __builtin_amdgcn_mfma_f32_16x16x32_bf16(au[mt][1], b1, sacc[mt][nti], 0, 0, 0);
        }
      }
    }
  }
  __syncthreads();  // s4: Aqu/Kt dead

  // ---- assembly: + E gather, masks, scale ----
  #pragma unroll
  for (int nti = 0; nti < 3; ++nti) {
    if (nti < nnt) {
      int colv = (wv + nti * 4) * 16 + l15;
      int jl = colv - (c + 4);
      bool cvalid = (colv < ncols) && !(jl >= 0 && jl >= lenlim);
      #pragma unroll
      for (int mt = 0; mt < 5; ++mt)
        #pragma unroll
        for (int r = 0; r < 4; ++r) {
          float s = sacc[mt][nti][r];
          if (cvalid) {
            if (mt < 4 && jl >= 0) {
              int m = mt * 16 + quad * 4 + r;
              s += __bfloat162float(Eb[m * 128 + (jl ^ (((m >> 2) & 7) << 4))]);
            }
            s *= 0.125f;
          } else s = -1e30f;
          sacc[mt][nti][r] = s;
        }
    }
  }

  // ---- softmax: row max ----
  {
    #pragma unroll
    for (int mt = 0; mt < 5; ++mt)
      #pragma unroll
      for (int r = 0; r < 4; ++r) {
        float v = -3e38f;
        #pragma unroll
        for (int nti = 0; nti < 3; ++nti)
          if (nti < nnt) v = fmaxf(v, sacc[mt][nti][r]);
        v = fmaxf(v, __shfl_xor(v, 1));
        v = fmaxf(v, __shfl_xor(v, 2));
        v = fmaxf(v, __shfl_xor(v, 4));
        v = fmaxf(v, __shfl_xor(v, 8));
        if (l15 == 0) wred[(mt * 16 + quad * 4 + r) * 4 + wv] = v;
      }
  }
  __syncthreads();  // s5
  if (tid < 80)
    rstat[tid] = fmaxf(fmaxf(wred[tid * 4], wred[tid * 4 + 1]),
                       fmaxf(wred[tid * 4 + 2], wred[tid * 4 + 3]));
  __syncthreads();  // s6

  // ---- softmax: exp, write P (bf16, stride 168), row sums ----
  {
    float rmx[5][4], rsum[5][4];
    #pragma unroll
    for (int mt = 0; mt < 5; ++mt)
      #pragma unroll
      for (int r = 0; r < 4; ++r) {
        rmx[mt][r] = rstat[mt * 16 + quad * 4 + r];
        rsum[mt][r] = 0.f;
      }
    #pragma unroll
    for (int nti = 0; nti < 3; ++nti) {
      if (nti < nnt) {
        int colv = (wv + nti * 4) * 16 + l15;
        #pragma unroll
        for (int mt = 0; mt < 5; ++mt)
          #pragma unroll
          for (int r = 0; r < 4; ++r) {
            float p = __expf(sacc[mt][nti][r] - rmx[mt][r]);
            Pp[(mt * 16 + quad * 4 + r) * 168 + colv] = __float2bfloat16(p);
            rsum[mt][r] += p;
          }
      }
    }
    #pragma unroll
    for (int mt = 0; mt < 5; ++mt)
      #pragma unroll
      for (int r = 0; r < 4; ++r) {
        float v = rsum[mt][r];
        v += __shfl_xor(v, 1);
        v += __shfl_xor(v, 2);
        v += __shfl_xor(v, 4);
        v += __shfl_xor(v, 8);
        if (l15 == 0) wred[(mt * 16 + quad * 4 + r) * 4 + wv] = v;
      }
  }
  __syncthreads();  // s7
  if (tid < 80)
    rstat[tid] = 1.f / (wred[tid * 4] + wred[tid * 4 + 1] + wred[tid * 4 + 2] + wred[tid * 4 + 3]);
  __syncthreads();  // s8

  // ---- PV GEMM: O[80 x 64] = P @ V ----
  const int kmax = (ncols + 31) >> 5;
  float4v oacc[5];
  #pragma unroll
  for (int mt = 0; mt < 5; ++mt) oacc[mt] = (float4v){0.f, 0.f, 0.f, 0.f};
  const int ehi = (wv * 16 + l15) >> 3, elo = l15 & 7;
  for (int ks = 0; ks < kmax; ++ks) {
    short8v bq;
    const int blk = ehi ^ ((ks * 4 + quad) & 7);
    #pragma unroll
    for (int j = 0; j < 8; ++j)
      bq[j] = ((const short*)Vs)[(ks * 32 + quad * 8 + j) * 64 + blk * 8 + elo];
    #pragma unroll
    for (int mt = 0; mt < 5; ++mt) {
      short8v af = *(const short8v*)&Pp[(mt * 16 + l15) * 168 + ks * 32 + quad * 8];
      oacc[mt] = __builtin_amdgcn_mfma_f32_16x16x32_bf16(af, bq, oacc[mt], 0, 0, 0);
    }
  }

  // ---- epilogue: rows m<68 -> attn; m==68 (summary) -> clipped d_out ----
  #pragma unroll
  for (int mt = 0; mt < 5; ++mt) {
    #pragma unroll
    for (int r = 0; r < 4; ++r) {
      int m = mt * 16 + quad * 4 + r;
      if (m >= 69) continue;
      float o = oacc[mt][r] * rstat[m];
      if (m < 68) {
        int qrow = (m < 64) ? (64 + 64 * c + m) : (4 * c + (m - 64));
        attn[((size_t)(qrow * 8 + b)) * 512 + h * 64 + wv * 16 + l15] = __float2bfloat16(o);
      } else {
        float v = fminf(fmaxf(o, -10.f), 10.f);
        size_t oi = (size_t)1088 * 8 * 512 + ((size_t)(c * 8 + b)) * 512 + h * 64 + wv * 16 + l15;
        if (obf) ((bf16*)dout)[oi] = __float2bfloat16(v);
        else     ((float*)dout)[oi] = v;
      }
    }
  }
}

static inline int cdiv(int a, int b) { return (a + b - 1) / b; }

extern "C" void kernel_launch(void* const* d_in, const int* in_sizes, int n_in,
                              void* d_out, int out_size, void* d_ws, size_t ws_size,
                              hipStream_t stream) {
  const void* utter = d_in[0];
  const int*  lens  = (const int*)d_in[1];
  const void* rctx  = d_in[2];
  const void* summ  = d_in[3];
  const void* memry = d_in[4];
  // d_in[5] attention_mask: analytic, never read
  const void* pose  = d_in[6];
  const void* W_kv  = d_in[7];
  const void* b_kv  = d_in[8];
  const void* W_q   = d_in[9];
  const void* b_q   = d_in[10];
  const void* W_out = d_in[11];
  const void* b_out = d_in[12];
  const void* W_pos = d_in[13];
  const void* pbu   = d_in[14];
  const void* pbv   = d_in[15];

  const unsigned SZ_MM = MM * BB * DD;   // 61440
  const unsigned SZ_RC = RR * BB * DD;   // 262144
  const unsigned SZ_UT = UU * BB * DD;   // 4194304
  const unsigned SZ_SM = SS * BB * DD;   // 65536
  const unsigned N_XU  = SZ_MM + SZ_RC + SZ_UT + SZ_SM;  // 4583424
  const unsigned SZ_PS = 191 * DD;       // 97792

  int*  flag = (int*)d_ws;
  bf16* base = (bf16*)((char*)d_ws + 64);
  unsigned off = 0;
  bf16* XU    = base + off; unsigned o_XU    = off; off += N_XU;
  bf16* posec = base + off; unsigned o_posec = off; off += 192 * DD;
  bf16* Wcat  = base + off; unsigned o_Wcat  = off; off += (unsigned)NU * DD;
  bf16* bcat  = base + off; unsigned o_bcat  = off; off += NU;
  bf16* Woutp = base + off; unsigned o_Wout  = off; off += DD * DD;
  bf16* boutp = base + off; unsigned o_bout  = off; off += DD;
  bf16* Wposp = base + off; unsigned o_Wpos  = off; off += DD * DD;
  bf16* pbuc  = base + off; unsigned o_pbu   = off; off += DD;
  bf16* pbvc  = base + off; unsigned o_pbv   = off; off += DD;
  bf16* qkv   = base + off; off += (unsigned)(MU + 8) * NU;  // 8960 x 1536
  bf16* pos   = base + off; off += 192 * DD;
  bf16* attn  = base + off; off += QQ * BB * DD;

  // Fused pack: 14 segments (union X = [mem | rc | utt | summ])
  PackDesc pd;
  const void* srcs[14]  = {memry, rctx, utter, summ, pose,
                           W_q, W_kv, b_q, b_kv, W_out, b_out, W_pos, pbu, pbv};
  unsigned    soffs[14] = {0, 0, 0, 0, 896u * DD, 0, 0, 0, 0, 0, 0, 0, 0, 0};
  unsigned    doffs[14] = {o_XU, o_XU + SZ_MM, o_XU + SZ_MM + SZ_RC,
                           o_XU + SZ_MM + SZ_RC + SZ_UT, o_posec,
                           o_Wcat, o_Wcat + DD * DD, o_bcat, o_bcat + DD,
                           o_Wout, o_bout, o_Wpos, o_pbu, o_pbv};
  unsigned    ns[14]    = {SZ_MM, SZ_RC, SZ_UT, SZ_SM, SZ_PS,
                           DD * DD, 2 * DD * DD, DD, 2 * DD,
                           DD * DD, DD, DD * DD, DD, DD};
  unsigned cum = 0;
  for (int i = 0; i < 14; ++i) {
    pd.src[i] = srcs[i]; pd.srcoff[i] = soffs[i]; pd.dstoff[i] = doffs[i];
    pd.cum[i] = cum; cum += ns[i] / 8;
  }
  pd.src[14] = pbv; pd.srcoff[14] = 0; pd.dstoff[14] = o_pbv;
  pd.src[15] = pbv; pd.srcoff[15] = 0; pd.dstoff[15] = o_pbv;
  pd.cum[14] = cum; pd.cum[15] = cum; pd.cum[16] = cum;
  int nchunks = (int)cum;
  pack_all<<<dim3(cdiv(nchunks, 256)), dim3(256), 0, stream>>>(pd, base, utter, flag, nchunks);

  // fused QKV GEMM (8952 x 1536) + pos GEMM (191 x 512) in one dispatch.
  // QKV region XCD-swizzled: needs ceil(70/8)*8=72 m-groups * 12 n -> 864 blocks
  GemmP gq{XU, Wcat, bcat, qkv, MU, NU, DD, nullptr};
  GemmP gp{posec, Wposp, nullptr, pos, 191, DD, DD, nullptr};
  gemm_dual<<<dim3(12, 73), dim3(256), 0, stream>>>(gq, gp, 72);

  // attention: one block per (c, b, h); writes attn rows + clipped summary rows
  attn_chunk<<<dim3(1024), dim3(256), 0, stream>>>(qkv, pos, pbuc, pbvc, lens, attn,
                                                   flag, d_out);

  // out_ru = attn[:1088] @ W_out^T + b_out (68 m-tiles -> 72 m-groups * 4 n)
  GemmP go{attn, Woutp, boutp, d_out, (RR + UU) * BB, DD, DD, flag};
  gemm_dual<<<dim3(4, 72), dim3(256), 0, stream>>>(go, go, 72);
}

// Round 11
// 199.456 us; speedup vs baseline: 1.3460x; 1.0652x over previous
//
#include <hip/hip_runtime.h>
#include <hip/hip_bf16.h>

typedef __hip_bfloat16 bf16;
typedef __attribute__((ext_vector_type(8))) short short8v;   // 8 bf16 (4 VGPRs)
typedef __attribute__((ext_vector_type(4))) float float4v;   // MFMA C/D frag

// Problem constants
#define UU 1024
#define BB 8
#define DD 512
#define HH 8
#define HD 64
#define RR 64
#define SS 16
#define MM 15
#define QQ 1104   // R + U + S
#define KVL 1103  // M + R + U
#define PEL 2047
#define NU 1536   // fused QKV output width
#define MU 8952   // union rows (15+64+1024+16)*8

#define AS1 __attribute__((address_space(1)))
#define AS3 __attribute__((address_space(3)))

__device__ __forceinline__ float lo16(unsigned u) { return __uint_as_float(u << 16); }
__device__ __forceinline__ float hi16(unsigned u) { return __uint_as_float(u & 0xffff0000u); }
__device__ __forceinline__ unsigned pk2(float a, float b) {
  unsigned short x = __builtin_bit_cast(unsigned short, __float2bfloat16(a));
  unsigned short y = __builtin_bit_cast(unsigned short, __float2bfloat16(b));
  return (unsigned)x | ((unsigned)y << 16);
}

// ---- fused canonicalization + in-block dtype detection ----
// NOTE: always copies into workspace (even for bf16). Measured (r6 vs r8):
// the copy acts as L2 prefetch + poison-flush absorber; zero-copy regressed
// the downstream GEMM by +35 us (WRITE_SIZE 27->70 MB).
struct PackDesc {
  const void* src[16];
  unsigned int srcoff[16];
  unsigned int dstoff[16];
  unsigned int cum[17];   // cumulative 8-element chunks
};

__global__ __launch_bounds__(256) void pack_all(PackDesc d, bf16* base,
                                                const void* __restrict__ probe,
                                                int* __restrict__ flagout,
                                                int nchunks) {
  __shared__ int wsum[4];
  const unsigned short* p = (const unsigned short*)probe;
  int big = 0;
  for (int i = threadIdx.x; i < 4096; i += 256)
    big += (((p[i] >> 7) & 0xFF) >= 137) ? 1 : 0;
  #pragma unroll
  for (int off = 32; off; off >>= 1) big += __shfl_down(big, off);
  if ((threadIdx.x & 63) == 0) wsum[threadIdx.x >> 6] = big;
  __syncthreads();
  const int flag = (wsum[0] + wsum[1] + wsum[2] + wsum[3] < 16) ? 1 : 0;
  if (threadIdx.x == 0 && blockIdx.x == 0) *flagout = flag;

  int g = blockIdx.x * 256 + threadIdx.x;
  if (g >= nchunks) return;
  int s = 0;
  #pragma unroll
  for (int i = 1; i < 17; ++i) s += (g >= d.cum[i]) ? 1 : 0;
  unsigned local = (g - d.cum[s]) * 8u;
  bf16* dst = base + d.dstoff[s] + local;
  if (flag) {
    const uint4 v = *(const uint4*)((const bf16*)d.src[s] + d.srcoff[s] + local);
    *(uint4*)dst = v;
  } else {
    const float* fp = (const float*)d.src[s] + d.srcoff[s] + local;
    uint4 o;
    o.x = pk2(fp[0], fp[1]);
    o.y = pk2(fp[2], fp[3]);
    o.z = pk2(fp[4], fp[5]);
    o.w = pk2(fp[6], fp[7]);
    *(uint4*)dst = o;
  }
}

// ---- MFMA GEMM, 64x128 tile, BK=128, XOR-swizzled LDS, 48KB -> 3 blocks/CU.
// Compute path identical to r7's (correctness-verified); XCD swizzle: bi&7
// sweeps all N-tiles of its own M-tiles so each A-tile lives in one XCD L2.
struct GemmP {
  const bf16* X; const bf16* W; const bf16* bias; void* out;
  int M, N, K; const int* outf;
};

__global__ __launch_bounds__(256, 3) void gemm_dual(GemmP g0, GemmP g1, int ysplit) {
  __shared__ bf16 As[64 * 128];
  __shared__ bf16 Bs[128 * 128];
  GemmP g; int bm, bn;
  if ((int)blockIdx.y < ysplit) {
    g = g0;
    int bi = (int)blockIdx.y * (int)gridDim.x + (int)blockIdx.x;
    int nbn = g0.N >> 7;
    int j = bi >> 3;
    int bmi = (bi & 7) + (j / nbn) * 8;
    int bni = j % nbn;
    if (bmi >= ((g0.M + 63) >> 6)) return;
    bm = bmi * 64; bn = bni * 128;
  } else {
    g = g1;
    int nt = g1.N >> 7;
    int bi = ((int)blockIdx.y - ysplit) * gridDim.x + blockIdx.x;
    if (bi >= ((g1.M + 63) >> 6) * nt) return;
    bm = (bi / nt) * 64; bn = (bi % nt) * 128;
  }
  const int tid = threadIdx.x;
  const int lane = tid & 63, wv = tid >> 6;
  const int wr = wv >> 1, wc = wv & 1;
  const int l4 = lane >> 4;            // row within 4-row staging group
  const int lb = lane & 15;            // 16B block within 256B row
  const int quad = lane >> 4, l15 = lane & 15;

  float4v acc[2][4] = {};

  for (int kb = 0; kb < g.K; kb += 128) {
    // stage A: 64 rows x 128 cols (16 KB)
    #pragma unroll
    for (int i = 0; i < 4; ++i) {
      int r = wv * 16 + i * 4 + l4;
      int gm = bm + r; if (gm > g.M - 1) gm = g.M - 1;
      const bf16* src = g.X + (size_t)gm * g.K + kb + ((lb ^ (r & 15)) * 8);
      __builtin_amdgcn_global_load_lds((const AS1 void*)src,
                                       (AS3 void*)&As[(wv * 16 + i * 4) * 128], 16, 0, 0);
    }
    // stage B: 128 rows x 128 cols (32 KB)
    #pragma unroll
    for (int i = 0; i < 8; ++i) {
      int r = wv * 32 + i * 4 + l4;
      int gn = bn + r; if (gn > g.N - 1) gn = g.N - 1;
      const bf16* src = g.W + (size_t)gn * g.K + kb + ((lb ^ (r & 15)) * 8);
      __builtin_amdgcn_global_load_lds((const AS1 void*)src,
                                       (AS3 void*)&Bs[(wv * 32 + i * 4) * 128], 16, 0, 0);
    }
    __syncthreads();
    #pragma unroll
    for (int ki = 0; ki < 4; ++ki) {
      const int slot = ((ki * 4 + quad) ^ l15) * 8;
      short8v a[2], bq[4];
      #pragma unroll
      for (int t = 0; t < 2; ++t)
        a[t] = *(const short8v*)&As[(wr * 32 + t * 16 + l15) * 128 + slot];
      #pragma unroll
      for (int t = 0; t < 4; ++t)
        bq[t] = *(const short8v*)&Bs[(wc * 64 + t * 16 + l15) * 128 + slot];
      #pragma unroll
      for (int mt = 0; mt < 2; ++mt)
        #pragma unroll
        for (int nt = 0; nt < 4; ++nt)
          acc[mt][nt] = __builtin_amdgcn_mfma_f32_16x16x32_bf16(
              a[mt], bq[nt], acc[mt][nt], 0, 0, 0);
    }
    __syncthreads();
  }

  const bool as_bf16 = (g.outf == nullptr) ? true : (*g.outf != 0);
  #pragma unroll
  for (int mt = 0; mt < 2; ++mt) {
    #pragma unroll
    for (int r = 0; r < 4; ++r) {
      int gm = bm + wr * 32 + mt * 16 + quad * 4 + r;
      if (gm >= g.M) continue;
      #pragma unroll
      for (int nt = 0; nt < 4; ++nt) {
        int gn = bn + wc * 64 + nt * 16 + l15;
        float v = acc[mt][nt][r];
        if (g.bias) v += __bfloat162float(g.bias[gn]);
        size_t o = (size_t)gm * g.N + gn;
        if (as_bf16) ((bf16*)g.out)[o] = __float2bfloat16(v);
        else         ((float*)g.out)[o] = v;
      }
    }
  }
}

// ---- MFMA chunk attention: one block per (c, b, h) ----
// VERBATIM round-9 version (passed @212us). r10's 47.9KB overlay NaN'd; do
// not re-attempt without isolating the overlay hazard.
__device__ __forceinline__ int gcol(int row, int c, int u0, int ncols) {
  if (row < c) return row;
  if (row < c + 4) return 15 + 4 * c + (row - c);
  if (row < ncols) return 79 + u0 + (row - c - 4);
  return 0;
}

__global__ __launch_bounds__(256, 2) void attn_chunk(
    const bf16* __restrict__ qkv, const bf16* __restrict__ pos,
    const bf16* __restrict__ pbu, const bf16* __restrict__ pbv,
    const int* __restrict__ lengths, bf16* __restrict__ attn,
    const int* __restrict__ flag, void* __restrict__ dout) {
  __shared__ char lds[65536];
  bf16* Vs   = (bf16*)(lds);           // [152][64]  (k>>3)-swizzled, whole life
  bf16* Aqu  = (bf16*)(lds + 19456);   // [80][64]   row&7-swizzled, whole life
  bf16* Kt   = (bf16*)(lds + 29696);   // [152][64]  row&7-swizzled, phase B
  bf16* Aqv  = (bf16*)(lds + 32768);   // [64][64]   row&7-swizzled, phase A
  bf16* Psl  = (bf16*)(lds + 40960);   // [192][64]  row&7-swizzled, phase A
  bf16* Eb   = (bf16*)(lds + 49152);   // [64][128]  bank-swizzled, phase B
  bf16* Pp   = (bf16*)(lds + 19456);   // [80][168]  softmax phase (over Aqu/Kt)
  float* wred  = (float*)(lds + 46336); // [80][4]
  float* rstat = (float*)(lds + 47616); // [80]

  const int idx = blockIdx.x;
  const int h = idx & 7, b = (idx >> 3) & 7, c = idx >> 6;
  const int u0 = c ? (c - 1) * 64 : 0;
  const int nut = c ? 128 : 64;
  const int ncols = c + 4 + nut;
  const int q0 = c ? 63 : 127;     // pos row p = q0 - m + jl
  const int tid = threadIdx.x, lane = tid & 63, wv = tid >> 6;
  const int quad = lane >> 4, l15 = lane & 15, key = l15 & 7;
  const int lenlim = lengths[b] - u0;
  const bool obf = (*flag != 0);

  // ---- stage V (152 rows, (k>>3)&7-swizzle) and PosSel (192 rows) ----
  {
    int lr = lane >> 3;
    int sbr = (lane & 7) ^ lr;
    for (int i = wv; i < 19; i += 4) {
      int row = i * 8 + lr;
      int g = gcol(row, c, u0, ncols);
      int sbv = (lane & 7) ^ (i & 7);
      const bf16* src = qkv + ((size_t)(g * 8 + b)) * NU + 1024 + h * 64 + sbv * 8;
      __builtin_amdgcn_global_load_lds((const AS1 void*)src, (AS3 void*)(Vs + i * 512), 16, 0, 0);
    }
    for (int i = wv; i < 24; i += 4) {
      int p = i * 8 + lr;
      const bf16* src = pos + (size_t)p * 512 + h * 64 + sbr * 8;
      __builtin_amdgcn_global_load_lds((const AS1 void*)src, (AS3 void*)(Psl + i * 512), 16, 0, 0);
    }
  }
  // ---- stage Aqu = q + pbu (80 rows), Aqv = q_utt + pbv (64 rows) ----
  for (int id = tid; id < 1152; id += 256) {
    bool isv = id >= 640;
    int lid = isv ? id - 640 : id;
    int m = lid >> 3, ec = lid & 7;
    int qrow;
    if (isv) qrow = 64 + 64 * c + m;
    else qrow = (m < 64) ? (64 + 64 * c + m)
              : (m < 68) ? (4 * c + (m - 64))
              : (m == 68) ? (1088 + c) : 0;
    const uint4 qa = *(const uint4*)(qkv + ((size_t)((qrow + 15) * 8 + b)) * NU + h * 64 + ec * 8);
    const uint4 ba = *(const uint4*)((isv ? pbv : pbu) + h * 64 + ec * 8);
    uint4 o;
    o.x = pk2(lo16(qa.x) + lo16(ba.x), hi16(qa.x) + hi16(ba.x));
    o.y = pk2(lo16(qa.y) + lo16(ba.y), hi16(qa.y) + hi16(ba.y));
    o.z = pk2(lo16(qa.z) + lo16(ba.z), hi16(qa.z) + hi16(ba.z));
    o.w = pk2(lo16(qa.w) + lo16(ba.w), hi16(qa.w) + hi16(ba.w));
    *(uint4*)((isv ? Aqv : Aqu) + m * 64 + (ec ^ (m & 7)) * 8) = o;
  }
  __syncthreads();  // s1

  // ---- E GEMM: E[64 x 192] = Aqv @ PosSel^T ----
  float4v eacc[4][3];
  #pragma unroll
  for (int mt = 0; mt < 4; ++mt)
    #pragma unroll
    for (int i = 0; i < 3; ++i) eacc[mt][i] = (float4v){0.f, 0.f, 0.f, 0.f};
  {
    short8v av[4][2];
    #pragma unroll
    for (int mt = 0; mt < 4; ++mt)
      #pragma unroll
      for (int ks = 0; ks < 2; ++ks)
        av[mt][ks] = *(const short8v*)&Aqv[(mt * 16 + l15) * 64 + ((ks * 4 + quad) ^ key) * 8];
    #pragma unroll
    for (int nti = 0; nti < 3; ++nti) {
      int nt = wv + nti * 4;
      short8v b0 = *(const short8v*)&Psl[(nt * 16 + l15) * 64 + (quad ^ key) * 8];
      short8v b1 = *(const short8v*)&Psl[(nt * 16 + l15) * 64 + ((4 + quad) ^ key) * 8];
      #pragma unroll
      for (int mt = 0; mt < 4; ++mt) {
        eacc[mt][nti] = __builtin_amdgcn_mfma_f32_16x16x32_bf16(av[mt][0], b0, eacc[mt][nti], 0, 0, 0);
        eacc[mt][nti] = __builtin_amdgcn_mfma_f32_16x16x32_bf16(av[mt][1], b1, eacc[mt][nti], 0, 0, 0);
      }
    }
  }
  __syncthreads();  // s2: Aqv/Psl dead

  // ---- stage K (row&7-swizzle) + scatter E into Eb (bank-swizzled) ----
  {
    int lr = lane >> 3, sbr = (lane & 7) ^ lr;
    for (int i = wv; i < 19; i += 4) {
      int row = i * 8 + lr;
      int g = gcol(row, c, u0, ncols);
      const bf16* src = qkv + ((size_t)(g * 8 + b)) * NU + 512 + h * 64 + sbr * 8;
      __builtin_amdgcn_global_load_lds((const AS1 void*)src, (AS3 void*)(Kt + i * 512), 16, 0, 0);
    }
  }
  #pragma unroll
  for (int nti = 0; nti < 3; ++nti) {
    int p = (wv + nti * 4) * 16 + l15;
    #pragma unroll
    for (int mt = 0; mt < 4; ++mt)
      #pragma unroll
      for (int r = 0; r < 4; ++r) {
        int m = mt * 16 + quad * 4 + r;
        int jl = p - q0 + m;
        if (jl >= 0 && jl < nut)
          Eb[m * 128 + (jl ^ (((m >> 2) & 7) << 4))] = __float2bfloat16(eacc[mt][nti][r]);
      }
  }
  __syncthreads();  // s3

  // ---- S GEMM: S[80 x 160] = Aqu @ K^T ----
  const int nnt = (wv < 2) ? 3 : 2;
  float4v sacc[5][3];
  #pragma unroll
  for (int mt = 0; mt < 5; ++mt)
    #pragma unroll
    for (int i = 0; i < 3; ++i) sacc[mt][i] = (float4v){0.f, 0.f, 0.f, 0.f};
  {
    short8v au[5][2];
    #pragma unroll
    for (int mt = 0; mt < 5; ++mt)
      #pragma unroll
      for (int ks = 0; ks < 2; ++ks)
        au[mt][ks] = *(const short8v*)&Aqu[(mt * 16 + l15) * 64 + ((ks * 4 + quad) ^ key) * 8];
    #pragma unroll
    for (int nti = 0; nti < 3; ++nti) {
      if (nti < nnt) {
        int nt = wv + nti * 4;
        short8v b0 = *(const short8v*)&Kt[(nt * 16 + l15) * 64 + (quad ^ key) * 8];
        short8v b1 = *(const short8v*)&Kt[(nt * 16 + l15) * 64 + ((4 + quad) ^ key) * 8];
        #pragma unroll
        for (int mt = 0; mt < 5; ++mt) {
          sacc[mt][nti] = __builtin_amdgcn_mfma_f32_16x16x32_bf16(au[mt][0], b0, sacc[mt][nti], 0, 0, 0);
          sacc[mt][nti] = __builtin_amdgcn_mfma_f32_16x16x32_bf16(au[mt][1], b1, sacc[mt][nti], 0, 0, 0);
        }
      }
    }
  }
  __syncthreads();  // s4: Aqu/Kt dead

  // ---- assembly: + E gather, masks, scale ----
  #pragma unroll
  for (int nti = 0; nti < 3; ++nti) {
    if (nti < nnt) {
      int colv = (wv + nti * 4) * 16 + l15;
      int jl = colv - (c + 4);
      bool cvalid = (colv < ncols) && !(jl >= 0 && jl >= lenlim);
      #pragma unroll
      for (int mt = 0; mt < 5; ++mt)
        #pragma unroll
        for (int r = 0; r < 4; ++r) {
          float s = sacc[mt][nti][r];
          if (cvalid) {
            if (mt < 4 && jl >= 0) {
              int m = mt * 16 + quad * 4 + r;
              s += __bfloat162float(Eb[m * 128 + (jl ^ (((m >> 2) & 7) << 4))]);
            }
            s *= 0.125f;
          } else s = -1e30f;
          sacc[mt][nti][r] = s;
        }
    }
  }

  // ---- softmax: row max ----
  {
    #pragma unroll
    for (int mt = 0; mt < 5; ++mt)
      #pragma unroll
      for (int r = 0; r < 4; ++r) {
        float v = -3e38f;
        #pragma unroll
        for (int nti = 0; nti < 3; ++nti)
          if (nti < nnt) v = fmaxf(v, sacc[mt][nti][r]);
        v = fmaxf(v, __shfl_xor(v, 1));
        v = fmaxf(v, __shfl_xor(v, 2));
        v = fmaxf(v, __shfl_xor(v, 4));
        v = fmaxf(v, __shfl_xor(v, 8));
        if (l15 == 0) wred[(mt * 16 + quad * 4 + r) * 4 + wv] = v;
      }
  }
  __syncthreads();  // s5
  if (tid < 80)
    rstat[tid] = fmaxf(fmaxf(wred[tid * 4], wred[tid * 4 + 1]),
                       fmaxf(wred[tid * 4 + 2], wred[tid * 4 + 3]));
  __syncthreads();  // s6

  // ---- softmax: exp, write P (bf16, stride 168), row sums ----
  {
    float rmx[5][4], rsum[5][4];
    #pragma unroll
    for (int mt = 0; mt < 5; ++mt)
      #pragma unroll
      for (int r = 0; r < 4; ++r) {
        rmx[mt][r] = rstat[mt * 16 + quad * 4 + r];
        rsum[mt][r] = 0.f;
      }
    #pragma unroll
    for (int nti = 0; nti < 3; ++nti) {
      if (nti < nnt) {
        int colv = (wv + nti * 4) * 16 + l15;
        #pragma unroll
        for (int mt = 0; mt < 5; ++mt)
          #pragma unroll
          for (int r = 0; r < 4; ++r) {
            float p = __expf(sacc[mt][nti][r] - rmx[mt][r]);
            Pp[(mt * 16 + quad * 4 + r) * 168 + colv] = __float2bfloat16(p);
            rsum[mt][r] += p;
          }
      }
    }
    #pragma unroll
    for (int mt = 0; mt < 5; ++mt)
      #pragma unroll
      for (int r = 0; r < 4; ++r) {
        float v = rsum[mt][r];
        v += __shfl_xor(v, 1);
        v += __shfl_xor(v, 2);
        v += __shfl_xor(v, 4);
        v += __shfl_xor(v, 8);
        if (l15 == 0) wred[(mt * 16 + quad * 4 + r) * 4 + wv] = v;
      }
  }
  __syncthreads();  // s7
  if (tid < 80)
    rstat[tid] = 1.f / (wred[tid * 4] + wred[tid * 4 + 1] + wred[tid * 4 + 2] + wred[tid * 4 + 3]);
  __syncthreads();  // s8

  // ---- PV GEMM: O[80 x 64] = P @ V ----
  const int kmax = (ncols + 31) >> 5;
  float4v oacc[5];
  #pragma unroll
  for (int mt = 0; mt < 5; ++mt) oacc[mt] = (float4v){0.f, 0.f, 0.f, 0.f};
  const int ehi = (wv * 16 + l15) >> 3, elo = l15 & 7;
  for (int ks = 0; ks < kmax; ++ks) {
    short8v bq;
    const int blk = ehi ^ ((ks * 4 + quad) & 7);
    #pragma unroll
    for (int j = 0; j < 8; ++j)
      bq[j] = ((const short*)Vs)[(ks * 32 + quad * 8 + j) * 64 + blk * 8 + elo];
    #pragma unroll
    for (int mt = 0; mt < 5; ++mt) {
      short8v af = *(const short8v*)&Pp[(mt * 16 + l15) * 168 + ks * 32 + quad * 8];
      oacc[mt] = __builtin_amdgcn_mfma_f32_16x16x32_bf16(af, bq, oacc[mt], 0, 0, 0);
    }
  }

  // ---- epilogue: rows m<68 -> attn; m==68 (summary) -> clipped d_out ----
  #pragma unroll
  for (int mt = 0; mt < 5; ++mt) {
    #pragma unroll
    for (int r = 0; r < 4; ++r) {
      int m = mt * 16 + quad * 4 + r;
      if (m >= 69) continue;
      float o = oacc[mt][r] * rstat[m];
      if (m < 68) {
        int qrow = (m < 64) ? (64 + 64 * c + m) : (4 * c + (m - 64));
        attn[((size_t)(qrow * 8 + b)) * 512 + h * 64 + wv * 16 + l15] = __float2bfloat16(o);
      } else {
        float v = fminf(fmaxf(o, -10.f), 10.f);
        size_t oi = (size_t)1088 * 8 * 512 + ((size_t)(c * 8 + b)) * 512 + h * 64 + wv * 16 + l15;
        if (obf) ((bf16*)dout)[oi] = __float2bfloat16(v);
        else     ((float*)dout)[oi] = v;
      }
    }
  }
}

static inline int cdiv(int a, int b) { return (a + b - 1) / b; }

extern "C" void kernel_launch(void* const* d_in, const int* in_sizes, int n_in,
                              void* d_out, int out_size, void* d_ws, size_t ws_size,
                              hipStream_t stream) {
  const void* utter = d_in[0];
  const int*  lens  = (const int*)d_in[1];
  const void* rctx  = d_in[2];
  const void* summ  = d_in[3];
  const void* memry = d_in[4];
  // d_in[5] attention_mask: analytic, never read
  const void* pose  = d_in[6];
  const void* W_kv  = d_in[7];
  const void* b_kv  = d_in[8];
  const void* W_q   = d_in[9];
  const void* b_q   = d_in[10];
  const void* W_out = d_in[11];
  const void* b_out = d_in[12];
  const void* W_pos = d_in[13];
  const void* pbu   = d_in[14];
  const void* pbv   = d_in[15];

  const unsigned SZ_MM = MM * BB * DD;   // 61440
  const unsigned SZ_RC = RR * BB * DD;   // 262144
  const unsigned SZ_UT = UU * BB * DD;   // 4194304
  const unsigned SZ_SM = SS * BB * DD;   // 65536
  const unsigned N_XU  = SZ_MM + SZ_RC + SZ_UT + SZ_SM;  // 4583424
  const unsigned SZ_PS = 191 * DD;       // 97792

  int*  flag = (int*)d_ws;
  bf16* base = (bf16*)((char*)d_ws + 64);
  unsigned off = 0;
  bf16* XU    = base + off; unsigned o_XU    = off; off += N_XU;
  bf16* posec = base + off; unsigned o_posec = off; off += 192 * DD;
  bf16* Wcat  = base + off; unsigned o_Wcat  = off; off += (unsigned)NU * DD;
  bf16* bcat  = base + off; unsigned o_bcat  = off; off += NU;
  bf16* Woutp = base + off; unsigned o_Wout  = off; off += DD * DD;
  bf16* boutp = base + off; unsigned o_bout  = off; off += DD;
  bf16* Wposp = base + off; unsigned o_Wpos  = off; off += DD * DD;
  bf16* pbuc  = base + off; unsigned o_pbu   = off; off += DD;
  bf16* pbvc  = base + off; unsigned o_pbv   = off; off += DD;
  bf16* qkv   = base + off; off += (unsigned)(MU + 8) * NU;
  bf16* pos   = base + off; off += 192 * DD;
  bf16* attn  = base + off; off += QQ * BB * DD;

  // Fused pack: 14 segments (union X = [mem | rc | utt | summ])
  PackDesc pd;
  const void* srcs[14]  = {memry, rctx, utter, summ, pose,
                           W_q, W_kv, b_q, b_kv, W_out, b_out, W_pos, pbu, pbv};
  unsigned    soffs[14] = {0, 0, 0, 0, 896u * DD, 0, 0, 0, 0, 0, 0, 0, 0, 0};
  unsigned    doffs[14] = {o_XU, o_XU + SZ_MM, o_XU + SZ_MM + SZ_RC,
                           o_XU + SZ_MM + SZ_RC + SZ_UT, o_posec,
                           o_Wcat, o_Wcat + DD * DD, o_bcat, o_bcat + DD,
                           o_Wout, o_bout, o_Wpos, o_pbu, o_pbv};
  unsigned    ns[14]    = {SZ_MM, SZ_RC, SZ_UT, SZ_SM, SZ_PS,
                           DD * DD, 2 * DD * DD, DD, 2 * DD,
                           DD * DD, DD, DD * DD, DD, DD};
  unsigned cum = 0;
  for (int i = 0; i < 14; ++i) {
    pd.src[i] = srcs[i]; pd.srcoff[i] = soffs[i]; pd.dstoff[i] = doffs[i];
    pd.cum[i] = cum; cum += ns[i] / 8;
  }
  pd.src[14] = pbv; pd.srcoff[14] = 0; pd.dstoff[14] = o_pbv;
  pd.src[15] = pbv; pd.srcoff[15] = 0; pd.dstoff[15] = o_pbv;
  pd.cum[14] = cum; pd.cum[15] = cum; pd.cum[16] = cum;
  int nchunks = (int)cum;
  pack_all<<<dim3(cdiv(nchunks, 256)), dim3(256), 0, stream>>>(pd, base, utter, flag, nchunks);

  // fused QKV GEMM (8952 x 1536, 64-row tiles: 140 m -> swizzle pad 144) + pos
  // pos: 191 rows -> 3 m-tiles * 4 n = 12 blocks -> one extra y row
  GemmP gq{XU, Wcat, bcat, qkv, MU, NU, DD, nullptr};
  GemmP gp{posec, Wposp, nullptr, pos, 191, DD, DD, nullptr};
  gemm_dual<<<dim3(12, 145), dim3(256), 0, stream>>>(gq, gp, 144);

  // attention: one block per (c, b, h); writes attn rows + clipped summary rows
  attn_chunk<<<dim3(1024), dim3(256), 0, stream>>>(qkv, pos, pbuc, pbvc, lens, attn,
                                                   flag, d_out);

  // out_ru = attn[:1088] @ W_out^T + b_out (136 m-tiles * 4 n = 544 blocks)
  GemmP go{attn, Woutp, boutp, d_out, (RR + UU) * BB, DD, DD, flag};
  gemm_dual<<<dim3(4, 136), dim3(256), 0, stream>>>(go, go, 136);
}